// Round 9
// baseline (267.868 us; speedup 1.0000x reference)
//
#include <hip/hip_runtime.h>
#include <math.h>

#define S_LEN 2064
#define S_PAD 2112               // 33 tiles * 64, zero-padded packed KV
#define NB 2
#define NH 9
#define NKV 3
#define HD 64
#define EMB 576
#define NTOK (NB*S_LEN)          // 4128
#define LSTR 68                  // padded f32 LDS stride
#define KSTR 72                  // bf16 LDS stride: 144B rows -> bank-balanced b128 reads

#define QSZ (NB*NH*S_LEN*HD)     // 2377728
#define KSZ (NB*NKV*S_LEN*HD)    // 792576
#define VSZ (NB*NKV*S_LEN*HD)    // 792576
#define ASZ (NB*S_LEN*EMB)       // 2377728
#define KPK (NB*NKV*S_PAD*HD)    // 811008 (per packed buffer, ushorts)

typedef float  f32x4  __attribute__((ext_vector_type(4)));
typedef short  s16x8  __attribute__((ext_vector_type(8)));

// f32 <-> bf16 (RNE), bit-level
static __device__ __forceinline__ ushort f2bf(float x) {
  union { float f; unsigned u; } a; a.f = x;
  unsigned r = a.u + 0x7fffu + ((a.u >> 16) & 1u);
  return (ushort)(r >> 16);
}
static __device__ __forceinline__ float bf2f(ushort h) {
  union { unsigned u; float f; } a; a.u = ((unsigned)h) << 16;
  return a.f;
}

// ---------------------------------------------------------------------------
// Fused QKV/Qr/Kr projection via MFMA, split-4 bf16 (unchanged from R8)
// ---------------------------------------------------------------------------
__global__ __launch_bounds__(256)
void proj_kernel(const float* __restrict__ x,
                 const float* __restrict__ qw, const float* __restrict__ kw,
                 const float* __restrict__ vw, const float* __restrict__ qrw,
                 const float* __restrict__ krw,
                 float* __restrict__ Qb, float* __restrict__ Kb,
                 float* __restrict__ Vb) {
  __shared__ __align__(16) ushort Xhi[64*KSTR];
  __shared__ __align__(16) ushort Xlo[64*KSTR];
  __shared__ __align__(16) ushort Whi[64*KSTR];
  __shared__ __align__(16) ushort Wlo[64*KSTR];

  const int tid  = threadIdx.x;
  const int wave = tid >> 6;
  const int lane = tid & 63;
  const int g    = lane >> 4;
  const int c    = lane & 15;

  const int m0 = blockIdx.x * 64;
  const int n0 = blockIdx.y * 64;

  const int srow = tid >> 2;
  const int sseg = (tid & 3) * 16;
  int gm = m0 + srow; if (gm > NTOK-1) gm = NTOK-1;
  const float* xrow = x + (size_t)gm * EMB;
  const int col = n0 + srow;
  const float* wrow;
  if (col < 504)      wrow = qw  + (size_t)col       * EMB;
  else if (col < 672) wrow = kw  + (size_t)(col-504) * EMB;
  else if (col < 864) wrow = vw  + (size_t)(col-672) * EMB;
  else if (col < 936) wrow = qrw + (size_t)(col-864) * EMB;
  else                wrow = krw + (size_t)(col-936) * EMB;

  f32x4 acc[4];
  #pragma unroll
  for (int n=0;n<4;++n) acc[n] = (f32x4){0.f,0.f,0.f,0.f};

  for (int kc0 = 0; kc0 < EMB; kc0 += 64) {
    __syncthreads();
    {
      float xv[16], wv[16];
      #pragma unroll
      for (int i=0;i<4;++i) {
        float4 x4 = *(const float4*)(xrow + kc0 + sseg + 4*i);
        float4 w4 = *(const float4*)(wrow + kc0 + sseg + 4*i);
        xv[4*i+0]=x4.x; xv[4*i+1]=x4.y; xv[4*i+2]=x4.z; xv[4*i+3]=x4.w;
        wv[4*i+0]=w4.x; wv[4*i+1]=w4.y; wv[4*i+2]=w4.z; wv[4*i+3]=w4.w;
      }
      uint xh[8], xl[8], wh[8], wl[8];
      #pragma unroll
      for (int m=0;m<8;++m) {
        ushort h0 = f2bf(xv[2*m]),   h1 = f2bf(xv[2*m+1]);
        ushort l0 = f2bf(xv[2*m]   - bf2f(h0));
        ushort l1 = f2bf(xv[2*m+1] - bf2f(h1));
        xh[m] = (uint)h0 | ((uint)h1 << 16);
        xl[m] = (uint)l0 | ((uint)l1 << 16);
        ushort g0 = f2bf(wv[2*m]),   g1 = f2bf(wv[2*m+1]);
        ushort k0 = f2bf(wv[2*m]   - bf2f(g0));
        ushort k1 = f2bf(wv[2*m+1] - bf2f(g1));
        wh[m] = (uint)g0 | ((uint)g1 << 16);
        wl[m] = (uint)k0 | ((uint)k1 << 16);
      }
      const int lo = srow*KSTR + sseg;
      *(uint4*)&Xhi[lo]     = make_uint4(xh[0],xh[1],xh[2],xh[3]);
      *(uint4*)&Xhi[lo + 8] = make_uint4(xh[4],xh[5],xh[6],xh[7]);
      *(uint4*)&Xlo[lo]     = make_uint4(xl[0],xl[1],xl[2],xl[3]);
      *(uint4*)&Xlo[lo + 8] = make_uint4(xl[4],xl[5],xl[6],xl[7]);
      *(uint4*)&Whi[lo]     = make_uint4(wh[0],wh[1],wh[2],wh[3]);
      *(uint4*)&Whi[lo + 8] = make_uint4(wh[4],wh[5],wh[6],wh[7]);
      *(uint4*)&Wlo[lo]     = make_uint4(wl[0],wl[1],wl[2],wl[3]);
      *(uint4*)&Wlo[lo + 8] = make_uint4(wl[4],wl[5],wl[6],wl[7]);
    }
    __syncthreads();

    #pragma unroll
    for (int kc=0; kc<2; ++kc) {
      const int d = kc*32 + g*8;
      s16x8 x_h = *(const s16x8*)&Xhi[(16*wave + c)*KSTR + d];
      s16x8 x_l = *(const s16x8*)&Xlo[(16*wave + c)*KSTR + d];
      #pragma unroll
      for (int n=0;n<4;++n) {
        s16x8 w_h = *(const s16x8*)&Whi[(16*n + c)*KSTR + d];
        s16x8 w_l = *(const s16x8*)&Wlo[(16*n + c)*KSTR + d];
        acc[n] = __builtin_amdgcn_mfma_f32_16x16x32_bf16(x_h, w_h, acc[n], 0, 0, 0);
        acc[n] = __builtin_amdgcn_mfma_f32_16x16x32_bf16(x_l, w_h, acc[n], 0, 0, 0);
        acc[n] = __builtin_amdgcn_mfma_f32_16x16x32_bf16(x_h, w_l, acc[n], 0, 0, 0);
        acc[n] = __builtin_amdgcn_mfma_f32_16x16x32_bf16(x_l, w_l, acc[n], 0, 0, 0);
      }
    }
  }

  #pragma unroll
  for (int r=0;r<4;++r) {
    const int row = m0 + 16*wave + 4*g + r;
    if (row >= NTOK) continue;
    const int b = row / S_LEN, s = row % S_LEN;
    #pragma unroll
    for (int n=0;n<4;++n) {
      const int cc = n0 + 16*n + c;
      const float v = acc[n][r];
      if (cc < 504) {
        int h = cc / 56, d = cc % 56;
        Qb[(((size_t)(b*NH+h))*S_LEN + s)*HD + d] = v;
      } else if (cc < 672) {
        int h = (cc-504)/56, d = (cc-504)%56;
        Kb[(((size_t)(b*NKV+h))*S_LEN + s)*HD + d] = v;
      } else if (cc < 864) {
        int h = (cc-672)/64, d = (cc-672)%64;
        Vb[(((size_t)(b*NKV+h))*S_LEN + s)*HD + d] = v;
      } else if (cc < 936) {
        int h = (cc-864)/8, d = 56 + (cc-864)%8;
        Qb[(((size_t)(b*NH+h))*S_LEN + s)*HD + d] = v;
      } else {
        int h = (cc-936)/8, d = 56 + (cc-936)%8;
        Kb[(((size_t)(b*NKV+h))*S_LEN + s)*HD + d] = v;
      }
    }
  }
}

// ---------------------------------------------------------------------------
// In-place partial RoPE on dims 56..63 of Q (9 heads) and K (3 heads).
// ---------------------------------------------------------------------------
__global__ void rope_kernel(float* __restrict__ Qb, float* __restrict__ Kb) {
  const int idx = blockIdx.x * blockDim.x + threadIdx.x;
  const int total = NB*(NH+NKV)*S_LEN;
  if (idx >= total) return;
  const int s  = idx % S_LEN;
  const int bh = idx / S_LEN;
  const int b  = bh / (NH+NKV), hh = bh % (NH+NKV);
  float* base;
  if (hh < NH) base = Qb + (((size_t)(b*NH + hh))*S_LEN + s)*HD + 56;
  else         base = Kb + (((size_t)(b*NKV + (hh-NH)))*S_LEN + s)*HD + 56;

  float4 a = *(const float4*)(base);
  float4 c = *(const float4*)(base + 4);
  float xv[8] = {a.x,a.y,a.z,a.w,c.x,c.y,c.z,c.w};
  const float es[4] = {0.0f, 2.0f/64.0f, 32.0f/64.0f, 34.0f/64.0f};
  const float ps = (float)s;
  float o[8];
  #pragma unroll
  for (int j=0;j<4;++j) {
    float th  = 1.0f / powf(100000.0f, es[j]);
    float ang = ps * th;
    float cs = cosf(ang), sn = sinf(ang);
    o[j]   = xv[j]*cs   - xv[j+4]*sn;
    o[j+4] = xv[j+4]*cs + xv[j]*sn;
  }
  *(float4*)(base)     = make_float4(o[0],o[1],o[2],o[3]);
  *(float4*)(base + 4) = make_float4(o[4],o[5],o[6],o[7]);
}

// ---------------------------------------------------------------------------
// 2-bit fake-quant of K (per 64-token group per dim, first 2048 tokens)
// ---------------------------------------------------------------------------
__global__ void quant_key_kernel(float* __restrict__ Kb) {
  const int wid  = (blockIdx.x * blockDim.x + threadIdx.x) >> 6;
  const int lane = threadIdx.x & 63;
  if (wid >= NB*NKV*32) return;
  const int bkh = wid >> 5, sg = wid & 31;
  float* base = Kb + ((size_t)bkh*S_LEN + sg*64)*HD + lane;
  float vals[64];
  float mn = 1e30f, mx = -1e30f;
  #pragma unroll
  for (int s=0;s<64;++s) {
    float v = fminf(fmaxf(base[s*HD], -10000.0f), 10000.0f);
    vals[s] = v;
    mn = fminf(mn, v); mx = fmaxf(mx, v);
  }
  float scale = (mx - mn) / 3.0f;
  if (scale == 0.0f) scale = 1.0f;
  #pragma unroll
  for (int s=0;s<64;++s) {
    float q = rintf((vals[s] - mn) / scale);
    base[s*HD] = q * scale + mn;
  }
}

// ---------------------------------------------------------------------------
// 2-bit fake-quant of V (per token over d=64, first 2032 tokens)
// ---------------------------------------------------------------------------
__global__ void quant_value_kernel(float* __restrict__ Vb) {
  const int wid  = (blockIdx.x * blockDim.x + threadIdx.x) >> 6;
  const int lane = threadIdx.x & 63;
  const int total = NB*NKV*2032;
  if (wid >= total) return;
  const int bkh = wid / 2032, s = wid % 2032;
  float* p = Vb + ((size_t)bkh*S_LEN + s)*HD + lane;
  float v = fminf(fmaxf(*p, -10000.0f), 10000.0f);
  float mn = v, mx = v;
  #pragma unroll
  for (int m=1;m<64;m<<=1) {
    mn = fminf(mn, __shfl_xor(mn, m));
    mx = fmaxf(mx, __shfl_xor(mx, m));
  }
  float scale = (mx - mn) / 3.0f;
  if (scale == 0.0f) scale = 1.0f;
  float q = rintf((v - mn) / scale);
  *p = q * scale + mn;
}

// ---------------------------------------------------------------------------
// Pack K (post-rope, post-quant) -> global bf16 hi/lo [bkv][S_PAD][64]
// ---------------------------------------------------------------------------
__global__ __launch_bounds__(256)
void pack_k_kernel(const float* __restrict__ Kb,
                   ushort* __restrict__ KhiG, ushort* __restrict__ KloG) {
  const int idx = blockIdx.x * blockDim.x + threadIdx.x;
  const int total = NB*NKV*S_PAD*8;
  if (idx >= total) return;
  const int bkv = idx / (S_PAD*8);
  const int rem = idx % (S_PAD*8);
  const int s = rem >> 3, d0 = (rem & 7) * 8;
  uint u_h[4], u_l[4];
  if (s < S_LEN) {
    const float* src = Kb + ((size_t)bkv*S_LEN + s)*HD + d0;
    float4 a = *(const float4*)(src);
    float4 b = *(const float4*)(src + 4);
    float v[8] = {a.x,a.y,a.z,a.w,b.x,b.y,b.z,b.w};
    ushort hb[8], lb[8];
    #pragma unroll
    for (int e=0;e<8;++e) {
      hb[e] = f2bf(v[e]);
      lb[e] = f2bf(v[e] - bf2f(hb[e]));
    }
    #pragma unroll
    for (int m=0;m<4;++m) {
      u_h[m] = (uint)hb[2*m] | ((uint)hb[2*m+1] << 16);
      u_l[m] = (uint)lb[2*m] | ((uint)lb[2*m+1] << 16);
    }
  } else {
    #pragma unroll
    for (int m=0;m<4;++m) { u_h[m] = 0; u_l[m] = 0; }
  }
  const size_t off = ((size_t)bkv*S_PAD + s)*HD + d0;
  *(uint4*)(KhiG + off) = make_uint4(u_h[0],u_h[1],u_h[2],u_h[3]);
  *(uint4*)(KloG + off) = make_uint4(u_l[0],u_l[1],u_l[2],u_l[3]);
}

// ---------------------------------------------------------------------------
// Pack V (post-quant) -> global TRANSPOSED bf16 (hi only) [bkv][64][S_PAD]
// ---------------------------------------------------------------------------
__global__ __launch_bounds__(256)
void pack_v_kernel(const float* __restrict__ Vb,
                   ushort* __restrict__ VhiT) {
  __shared__ float T[64*LSTR];     // [key][d]
  const int tid = threadIdx.x;
  const int bkv = blockIdx.x / 33;
  const int kt  = blockIdx.x % 33;
  const int kbase = kt * 64;

  {  // coalesced read of 64x64 f32 tile
    const int key = tid >> 2, c16 = (tid & 3) * 16;
    const int s = kbase + key;
    if (s < S_LEN) {
      const float* src = Vb + ((size_t)bkv*S_LEN + s)*HD + c16;
      #pragma unroll
      for (int i=0;i<4;++i) {
        float4 v = *(const float4*)(src + 4*i);
        *(float4*)(T + key*LSTR + c16 + 4*i) = v;
      }
    } else {
      #pragma unroll
      for (int i=0;i<4;++i)
        *(float4*)(T + key*LSTR + c16 + 4*i) = make_float4(0.f,0.f,0.f,0.f);
    }
  }
  __syncthreads();
  {  // write transposed rows (d-major), 16 keys per thread
    const int d = tid >> 2, seg = tid & 3;
    ushort hb[16];
    #pragma unroll
    for (int kk=0;kk<16;++kk)
      hb[kk] = f2bf(T[(seg*16 + kk)*LSTR + d]);
    uint uh[8];
    #pragma unroll
    for (int m=0;m<8;++m)
      uh[m] = (uint)hb[2*m] | ((uint)hb[2*m+1] << 16);
    const size_t off = ((size_t)bkv*HD + d)*S_PAD + kbase + seg*16;
    *(uint4*)(VhiT + off)     = make_uint4(uh[0],uh[1],uh[2],uh[3]);
    *(uint4*)(VhiT + off + 8) = make_uint4(uh[4],uh[5],uh[6],uh[7]);
  }
}

// ---------------------------------------------------------------------------
// Flash attention v3: paired q-tiles + stage-once/compute-twice + LDS double
// buffer with early-issued register prefetch (plain-HIP T14 pattern).
//   Block p handles q-tiles {p, 32-p} (p=16 -> {16} only): every pair does
//   exactly 34 tile-computations over 33 staged k-tiles -> balanced grid,
//   staging amortized over 2x compute, HBM latency hidden under compute.
//   Numerics identical to R8: QK split-3 bf16, PV plain bf16.
// LDS: 2x(Khi,Klo,Vhi) + Phi = 63 KB -> 2 blocks/CU. Grid 17 x 18 = 306.
// ---------------------------------------------------------------------------
__global__ __launch_bounds__(256)
void attn_kernel(const float* __restrict__ Q,
                 const ushort* __restrict__ KhiG, const ushort* __restrict__ KloG,
                 const ushort* __restrict__ VhiT,
                 float* __restrict__ A) {
  __shared__ __align__(16) ushort Khi[2][64*KSTR];
  __shared__ __align__(16) ushort Klo[2][64*KSTR];
  __shared__ __align__(16) ushort Vhi[2][64*KSTR];
  __shared__ __align__(16) ushort Phi[64*KSTR];

  const int tid  = threadIdx.x;
  const int wave = tid >> 6;
  const int lane = tid & 63;
  const int g    = lane >> 4;      // k-group / row-group
  const int c    = lane & 15;      // col (B/D) / row (A) lane index

  const int p   = blockIdx.x;              // 0..16
  const int qtb = 32 - p;                  // heavy tile: 32..16
  const int qta = (p < 16) ? p : -1;       // light tile: 0..15, or none
  const int bh = blockIdx.y;
  const int b = bh / NH, h = bh % NH, kvh = h / (NH/NKV);
  const int bkv = b*NKV + kvh;
  const float* Qg = Q + ((size_t)(b*NH + h)*S_LEN)*HD;
  const ushort* KhiB = KhiG + (size_t)bkv*S_PAD*HD;
  const ushort* KloB = KloG + (size_t)bkv*S_PAD*HD;
  const ushort* VhiB = VhiT + (size_t)bkv*HD*S_PAD;

  // ---- Q fragments for both tiles (hi+lo split), A row = c
  s16x8 qhiA[2], qloA[2], qhiB2[2], qloB2[2];
  auto loadQ = [&](int qbase, s16x8* qhi, s16x8* qlo) {
    int qrow = qbase + 16*wave + c;
    if (qrow > S_LEN-1) qrow = S_LEN-1;
    #pragma unroll
    for (int kc = 0; kc < 2; ++kc) {
      const float* qp = Qg + (size_t)qrow*HD + kc*32 + g*8;
      float4 q0 = *(const float4*)(qp);
      float4 q1 = *(const float4*)(qp + 4);
      float qv[8] = {q0.x,q0.y,q0.z,q0.w,q1.x,q1.y,q1.z,q1.w};
      #pragma unroll
      for (int e=0;e<8;++e) {
        ushort hi = f2bf(qv[e]);
        ushort lo = f2bf(qv[e] - bf2f(hi));
        qhi[kc][e] = (short)hi;
        qlo[kc][e] = (short)lo;
      }
    }
  };
  loadQ((qta >= 0 ? qta : 0)*64, qhiA, qloA);
  loadQ(qtb*64, qhiB2, qloB2);

  f32x4 accA[4], accB[4];
  float mA[4], lA[4], mB[4], lB[4];
  #pragma unroll
  for (int n=0;n<4;++n) { accA[n] = (f32x4){0.f,0.f,0.f,0.f}; accB[n] = (f32x4){0.f,0.f,0.f,0.f}; }
  #pragma unroll
  for (int r=0;r<4;++r) { mA[r] = -INFINITY; lA[r] = 0.f; mB[r] = -INFINITY; lB[r] = 0.f; }

  // staging: thread t handles rows (t>>3) and (t>>3)+32, 8-elem seg (t&7)*8
  const int srow = tid >> 3;
  const int sseg = (tid & 7) * 8;
  uint4 pk_h[2], pk_l[2], pv_h[2];
  auto stage_load = [&](int kbase) {
    #pragma unroll
    for (int it=0; it<2; ++it) {
      const int r = srow + 32*it;
      const size_t kg = ((size_t)(kbase + r))*HD + sseg;
      pk_h[it] = *(const uint4*)(KhiB + kg);
      pk_l[it] = *(const uint4*)(KloB + kg);
      const size_t vg = (size_t)r*S_PAD + kbase + sseg;
      pv_h[it] = *(const uint4*)(VhiB + vg);
    }
  };
  auto stage_write = [&](int buf) {
    #pragma unroll
    for (int it=0; it<2; ++it) {
      const int r = srow + 32*it;
      *(uint4*)&Khi[buf][r*KSTR + sseg] = pk_h[it];
      *(uint4*)&Klo[buf][r*KSTR + sseg] = pk_l[it];
      *(uint4*)&Vhi[buf][r*KSTR + sseg] = pv_h[it];
    }
  };

  // one k-tile of work for one q-tile (QK split-3, softmax, PV bf16)
  auto process = [&](int buf, int kbase, int qbase, bool diag,
                     s16x8 (&qhi)[2], s16x8 (&qlo)[2],
                     f32x4 (&acc)[4], float (&m_i)[4], float (&l_i)[4]) {
    f32x4 sc[4];
    #pragma unroll
    for (int n=0;n<4;++n) sc[n] = (f32x4){0.f,0.f,0.f,0.f};
    #pragma unroll
    for (int kc=0; kc<2; ++kc) {
      #pragma unroll
      for (int n=0;n<4;++n) {
        const int key = 16*n + c;
        const int d   = kc*32 + g*8;
        s16x8 khf = *(const s16x8*)&Khi[buf][key*KSTR + d];
        s16x8 klf = *(const s16x8*)&Klo[buf][key*KSTR + d];
        sc[n] = __builtin_amdgcn_mfma_f32_16x16x32_bf16(qhi[kc], khf, sc[n], 0, 0, 0);
        sc[n] = __builtin_amdgcn_mfma_f32_16x16x32_bf16(qlo[kc], khf, sc[n], 0, 0, 0);
        sc[n] = __builtin_amdgcn_mfma_f32_16x16x32_bf16(qhi[kc], klf, sc[n], 0, 0, 0);
      }
    }
    #pragma unroll
    for (int r=0;r<4;++r) {
      const int grow = qbase + 16*wave + 4*g + r;   // unclamped (mask-consistent)
      float s[4];
      #pragma unroll
      for (int n=0;n<4;++n) {
        float sv = sc[n][r] * 0.125f;
        if (diag && (kbase + 16*n + c > grow)) sv = -INFINITY;
        s[n] = sv;
      }
      float rm = fmaxf(fmaxf(s[0],s[1]), fmaxf(s[2],s[3]));
      rm = fmaxf(rm, __shfl_xor(rm, 1));
      rm = fmaxf(rm, __shfl_xor(rm, 2));
      rm = fmaxf(rm, __shfl_xor(rm, 4));
      rm = fmaxf(rm, __shfl_xor(rm, 8));
      const float mn = fmaxf(m_i[r], rm);
      const float al = __expf(m_i[r] - mn);   // exp(-inf)=0 on first tile
      float sum = 0.f;
      float pv4[4];
      #pragma unroll
      for (int n=0;n<4;++n) {
        float pv = __expf(s[n] - mn);
        pv4[n] = pv;
        sum += pv;
      }
      sum += __shfl_xor(sum, 1);
      sum += __shfl_xor(sum, 2);
      sum += __shfl_xor(sum, 4);
      sum += __shfl_xor(sum, 8);
      l_i[r] = l_i[r]*al + sum;
      m_i[r] = mn;
      #pragma unroll
      for (int n=0;n<4;++n) acc[n][r] *= al;
      // P rows are wave-private (write rows 16w+*, read rows 16w+*): no barrier
      #pragma unroll
      for (int n=0;n<4;++n)
        Phi[(16*wave + 4*g + r)*KSTR + 16*n + c] = f2bf(pv4[n]);
    }
    #pragma unroll
    for (int kc=0; kc<2; ++kc) {
      const int pd = kc*32 + g*8;
      s16x8 pfh = *(const s16x8*)&Phi[(16*wave + c)*KSTR + pd];
      #pragma unroll
      for (int n=0;n<4;++n) {
        s16x8 vfh = *(const s16x8*)&Vhi[buf][(16*n + c)*KSTR + pd];
        acc[n] = __builtin_amdgcn_mfma_f32_16x16x32_bf16(pfh, vfh, acc[n], 0, 0, 0);
      }
    }
  };

  // ---- prologue: stage tile 0 into buf 0
  stage_load(0);
  stage_write(0);
  int cur = 0;

  // ---- main loop: one barrier per k-tile; prefetch kt+1 under compute
  for (int kt = 0; kt <= qtb; ++kt) {
    __syncthreads();                       // buf[cur] visible; buf[cur^1] free
    if (kt < qtb) stage_load((kt+1)*64);   // issue early: latency under compute
    if (kt <= qta)
      process(cur, kt*64, qta*64, kt==qta, qhiA, qloA, accA, mA, lA);
    process(cur, kt*64, qtb*64, kt==qtb, qhiB2, qloB2, accB, mB, lB);
    if (kt < qtb) stage_write(cur^1);      // compiler waits vmcnt on reg use
    cur ^= 1;
  }

  // ---- epilogue: divide by l, write A (b, s, h*64+d)
  auto epi = [&](int qbase, f32x4 (&acc)[4], float (&l_i)[4]) {
    #pragma unroll
    for (int r=0;r<4;++r) {
      const int grow = qbase + 16*wave + 4*g + r;
      if (grow < S_LEN) {
        const float inv = 1.0f / l_i[r];
        #pragma unroll
        for (int n=0;n<4;++n)
          A[((size_t)(b*S_LEN + grow))*EMB + h*HD + 16*n + c] = acc[n][r] * inv;
      }
    }
  };
  if (qta >= 0) epi(qta*64, accA, lA);
  epi(qtb*64, accB, lB);
}

// ---------------------------------------------------------------------------
// Output projection via MFMA (split-bf16 3-term): out = A @ o_w^T
// ---------------------------------------------------------------------------
__global__ __launch_bounds__(256)
void oproj_kernel(const float* __restrict__ A, const float* __restrict__ ow,
                  float* __restrict__ out) {
  __shared__ __align__(16) ushort Ahi[64*KSTR];
  __shared__ __align__(16) ushort Alo[64*KSTR];
  __shared__ __align__(16) ushort Whi[64*KSTR];
  __shared__ __align__(16) ushort Wlo[64*KSTR];

  const int tid  = threadIdx.x;
  const int wave = tid >> 6;
  const int lane = tid & 63;
  const int g    = lane >> 4;
  const int c    = lane & 15;

  const int m0 = blockIdx.x * 64;
  const int n0 = blockIdx.y * 64;

  const int srow = tid >> 2;
  const int sseg = (tid & 3) * 16;
  int am = m0 + srow; if (am > NTOK-1) am = NTOK-1;
  const float* arow = A  + (size_t)am * EMB;
  const float* wrow = ow + (size_t)(n0 + srow) * EMB;   // always in-bounds (N=576)

  f32x4 acc[4];
  #pragma unroll
  for (int n=0;n<4;++n) acc[n] = (f32x4){0.f,0.f,0.f,0.f};

  for (int kc0 = 0; kc0 < EMB; kc0 += 64) {
    __syncthreads();
    {
      float av[16], wv[16];
      #pragma unroll
      for (int i=0;i<4;++i) {
        float4 a4 = *(const float4*)(arow + kc0 + sseg + 4*i);
        float4 w4 = *(const float4*)(wrow + kc0 + sseg + 4*i);
        av[4*i+0]=a4.x; av[4*i+1]=a4.y; av[4*i+2]=a4.z; av[4*i+3]=a4.w;
        wv[4*i+0]=w4.x; wv[4*i+1]=w4.y; wv[4*i+2]=w4.z; wv[4*i+3]=w4.w;
      }
      uint ah[8], al[8], wh[8], wl[8];
      #pragma unroll
      for (int m=0;m<8;++m) {
        ushort h0 = f2bf(av[2*m]),   h1 = f2bf(av[2*m+1]);
        ushort l0 = f2bf(av[2*m]   - bf2f(h0));
        ushort l1 = f2bf(av[2*m+1] - bf2f(h1));
        ah[m] = (uint)h0 | ((uint)h1 << 16);
        al[m] = (uint)l0 | ((uint)l1 << 16);
        ushort g0 = f2bf(wv[2*m]),   g1 = f2bf(wv[2*m+1]);
        ushort m0_ = f2bf(wv[2*m]   - bf2f(g0));
        ushort m1_ = f2bf(wv[2*m+1] - bf2f(g1));
        wh[m] = (uint)g0 | ((uint)g1 << 16);
        wl[m] = (uint)m0_ | ((uint)m1_ << 16);
      }
      const int lo = srow*KSTR + sseg;
      *(uint4*)&Ahi[lo]     = make_uint4(ah[0],ah[1],ah[2],ah[3]);
      *(uint4*)&Ahi[lo + 8] = make_uint4(ah[4],ah[5],ah[6],ah[7]);
      *(uint4*)&Alo[lo]     = make_uint4(al[0],al[1],al[2],al[3]);
      *(uint4*)&Alo[lo + 8] = make_uint4(al[4],al[5],al[6],al[7]);
      *(uint4*)&Whi[lo]     = make_uint4(wh[0],wh[1],wh[2],wh[3]);
      *(uint4*)&Whi[lo + 8] = make_uint4(wh[4],wh[5],wh[6],wh[7]);
      *(uint4*)&Wlo[lo]     = make_uint4(wl[0],wl[1],wl[2],wl[3]);
      *(uint4*)&Wlo[lo + 8] = make_uint4(wl[4],wl[5],wl[6],wl[7]);
    }
    __syncthreads();

    #pragma unroll
    for (int kc=0; kc<2; ++kc) {
      const int d = kc*32 + g*8;
      s16x8 a_h = *(const s16x8*)&Ahi[(16*wave + c)*KSTR + d];
      s16x8 a_l = *(const s16x8*)&Alo[(16*wave + c)*KSTR + d];
      #pragma unroll
      for (int n=0;n<4;++n) {
        s16x8 w_h = *(const s16x8*)&Whi[(16*n + c)*KSTR + d];
        s16x8 w_l = *(const s16x8*)&Wlo[(16*n + c)*KSTR + d];
        acc[n] = __builtin_amdgcn_mfma_f32_16x16x32_bf16(a_h, w_h, acc[n], 0, 0, 0);
        acc[n] = __builtin_amdgcn_mfma_f32_16x16x32_bf16(a_l, w_h, acc[n], 0, 0, 0);
        acc[n] = __builtin_amdgcn_mfma_f32_16x16x32_bf16(a_h, w_l, acc[n], 0, 0, 0);
      }
    }
  }

  #pragma unroll
  for (int r=0;r<4;++r) {
    const int m = m0 + 16*wave + 4*g + r;
    if (m < NTOK) {
      #pragma unroll
      for (int n=0;n<4;++n)
        out[(size_t)m*EMB + n0 + 16*n + c] = acc[n][r];
    }
  }
}

// ---------------------------------------------------------------------------
extern "C" void kernel_launch(void* const* d_in, const int* in_sizes, int n_in,
                              void* d_out, int out_size, void* d_ws, size_t ws_size,
                              hipStream_t stream) {
  const float* x   = (const float*)d_in[0];
  const float* qw  = (const float*)d_in[1];
  const float* kw  = (const float*)d_in[2];
  const float* vw  = (const float*)d_in[3];
  const float* qrw = (const float*)d_in[4];
  const float* krw = (const float*)d_in[5];
  const float* ow  = (const float*)d_in[6];
  float* out = (float*)d_out;

  float* ws = (float*)d_ws;
  float* Qb = ws;
  float* Kb = Qb + QSZ;
  float* Vb = Kb + KSZ;
  float* Ab = Vb + VSZ;
  ushort* KhiG = (ushort*)(Ab + ASZ);
  ushort* KloG = KhiG + KPK;
  ushort* VhiT = KloG + KPK;

  // 1. fused projections (MFMA split-4)
  dim3 g1((NTOK + 63)/64, 960/64);            // 65 x 15
  proj_kernel<<<g1, 256, 0, stream>>>(x, qw, kw, vw, qrw, krw, Qb, Kb, Vb);

  // 2. rope on q_r / k_r
  {
    int total = NB*(NH+NKV)*S_LEN;
    rope_kernel<<<(total+255)/256, 256, 0, stream>>>(Qb, Kb);
  }

  // 3. fake-quant K (first 2048) and V (first 2032)
  {
    int kwaves = NB*NKV*32;
    quant_key_kernel<<<(kwaves*64+255)/256, 256, 0, stream>>>(Kb);
    int vwaves = NB*NKV*2032;
    quant_value_kernel<<<(vwaves*64+255)/256, 256, 0, stream>>>(Vb);
  }

  // 4. pack KV (K hi/lo row-major; V hi transposed), zero-padded
  {
    int ksegs = NB*NKV*S_PAD*8;
    pack_k_kernel<<<(ksegs+255)/256, 256, 0, stream>>>(Kb, KhiG, KloG);
    pack_v_kernel<<<NB*NKV*33, 256, 0, stream>>>(Vb, VhiT);
  }

  // 5. causal flash attention (paired q-tiles, double-buffered)
  dim3 ga(17, NB*NH);                          // 306 balanced blocks
  attn_kernel<<<ga, 256, 0, stream>>>(Qb, KhiG, KloG, VhiT, Ab);

  // 6. output projection (MFMA, split-bf16)
  dim3 go((NTOK + 63)/64, EMB/64);             // 65 x 9
  oproj_kernel<<<go, 256, 0, stream>>>(Ab, ow, out);
}

// Round 10
// 220.368 us; speedup vs baseline: 1.2155x; 1.2155x over previous
//
#include <hip/hip_runtime.h>
#include <math.h>

#define S_LEN 2064
#define S_PAD 2112               // 33 tiles * 64, zero-padded packed KV
#define NB 2
#define NH 9
#define NKV 3
#define HD 64
#define EMB 576
#define NTOK (NB*S_LEN)          // 4128
#define LSTR 68                  // padded f32 LDS stride
#define KSTR 72                  // bf16 LDS stride: 144B rows -> bank-balanced b128 reads

#define QSZ (NB*NH*S_LEN*HD)     // 2377728
#define KSZ (NB*NKV*S_LEN*HD)    // 792576
#define VSZ (NB*NKV*S_LEN*HD)    // 792576
#define ASZ (NB*S_LEN*EMB)       // 2377728
#define KPK (NB*NKV*S_PAD*HD)    // 811008 (per packed buffer, ushorts)

#define NSLOT_BH 85              // sum over qt of ceil((qt+1)/8)
#define NSLOTS (NB*NH*NSLOT_BH)  // 1530 partial slots

typedef float  f32x4  __attribute__((ext_vector_type(4)));
typedef short  s16x8  __attribute__((ext_vector_type(8)));

// f32 <-> bf16 (RNE), bit-level
static __device__ __forceinline__ ushort f2bf(float x) {
  union { float f; unsigned u; } a; a.f = x;
  unsigned r = a.u + 0x7fffu + ((a.u >> 16) & 1u);
  return (ushort)(r >> 16);
}
static __device__ __forceinline__ float bf2f(ushort h) {
  union { unsigned u; float f; } a; a.u = ((unsigned)h) << 16;
  return a.f;
}
// cumulative chunk count before q-tile qt (CK=8): sum_{i=1..qt} ceil(i/8)
static __device__ __forceinline__ int cum8(int qt) {
  int a = qt >> 3, b = qt & 7;
  return (a + 1) * (4 * a + b);
}

// ---------------------------------------------------------------------------
// Fused QKV/Qr/Kr projection via MFMA, split-4 bf16 (unchanged from R8)
// ---------------------------------------------------------------------------
__global__ __launch_bounds__(256)
void proj_kernel(const float* __restrict__ x,
                 const float* __restrict__ qw, const float* __restrict__ kw,
                 const float* __restrict__ vw, const float* __restrict__ qrw,
                 const float* __restrict__ krw,
                 float* __restrict__ Qb, float* __restrict__ Kb,
                 float* __restrict__ Vb) {
  __shared__ __align__(16) ushort Xhi[64*KSTR];
  __shared__ __align__(16) ushort Xlo[64*KSTR];
  __shared__ __align__(16) ushort Whi[64*KSTR];
  __shared__ __align__(16) ushort Wlo[64*KSTR];

  const int tid  = threadIdx.x;
  const int wave = tid >> 6;
  const int lane = tid & 63;
  const int g    = lane >> 4;
  const int c    = lane & 15;

  const int m0 = blockIdx.x * 64;
  const int n0 = blockIdx.y * 64;

  const int srow = tid >> 2;
  const int sseg = (tid & 3) * 16;
  int gm = m0 + srow; if (gm > NTOK-1) gm = NTOK-1;
  const float* xrow = x + (size_t)gm * EMB;
  const int col = n0 + srow;
  const float* wrow;
  if (col < 504)      wrow = qw  + (size_t)col       * EMB;
  else if (col < 672) wrow = kw  + (size_t)(col-504) * EMB;
  else if (col < 864) wrow = vw  + (size_t)(col-672) * EMB;
  else if (col < 936) wrow = qrw + (size_t)(col-864) * EMB;
  else                wrow = krw + (size_t)(col-936) * EMB;

  f32x4 acc[4];
  #pragma unroll
  for (int n=0;n<4;++n) acc[n] = (f32x4){0.f,0.f,0.f,0.f};

  for (int kc0 = 0; kc0 < EMB; kc0 += 64) {
    __syncthreads();
    {
      float xv[16], wv[16];
      #pragma unroll
      for (int i=0;i<4;++i) {
        float4 x4 = *(const float4*)(xrow + kc0 + sseg + 4*i);
        float4 w4 = *(const float4*)(wrow + kc0 + sseg + 4*i);
        xv[4*i+0]=x4.x; xv[4*i+1]=x4.y; xv[4*i+2]=x4.z; xv[4*i+3]=x4.w;
        wv[4*i+0]=w4.x; wv[4*i+1]=w4.y; wv[4*i+2]=w4.z; wv[4*i+3]=w4.w;
      }
      uint xh[8], xl[8], wh[8], wl[8];
      #pragma unroll
      for (int m=0;m<8;++m) {
        ushort h0 = f2bf(xv[2*m]),   h1 = f2bf(xv[2*m+1]);
        ushort l0 = f2bf(xv[2*m]   - bf2f(h0));
        ushort l1 = f2bf(xv[2*m+1] - bf2f(h1));
        xh[m] = (uint)h0 | ((uint)h1 << 16);
        xl[m] = (uint)l0 | ((uint)l1 << 16);
        ushort g0 = f2bf(wv[2*m]),   g1 = f2bf(wv[2*m+1]);
        ushort k0 = f2bf(wv[2*m]   - bf2f(g0));
        ushort k1 = f2bf(wv[2*m+1] - bf2f(g1));
        wh[m] = (uint)g0 | ((uint)g1 << 16);
        wl[m] = (uint)k0 | ((uint)k1 << 16);
      }
      const int lo = srow*KSTR + sseg;
      *(uint4*)&Xhi[lo]     = make_uint4(xh[0],xh[1],xh[2],xh[3]);
      *(uint4*)&Xhi[lo + 8] = make_uint4(xh[4],xh[5],xh[6],xh[7]);
      *(uint4*)&Xlo[lo]     = make_uint4(xl[0],xl[1],xl[2],xl[3]);
      *(uint4*)&Xlo[lo + 8] = make_uint4(xl[4],xl[5],xl[6],xl[7]);
      *(uint4*)&Whi[lo]     = make_uint4(wh[0],wh[1],wh[2],wh[3]);
      *(uint4*)&Whi[lo + 8] = make_uint4(wh[4],wh[5],wh[6],wh[7]);
      *(uint4*)&Wlo[lo]     = make_uint4(wl[0],wl[1],wl[2],wl[3]);
      *(uint4*)&Wlo[lo + 8] = make_uint4(wl[4],wl[5],wl[6],wl[7]);
    }
    __syncthreads();

    #pragma unroll
    for (int kc=0; kc<2; ++kc) {
      const int d = kc*32 + g*8;
      s16x8 x_h = *(const s16x8*)&Xhi[(16*wave + c)*KSTR + d];
      s16x8 x_l = *(const s16x8*)&Xlo[(16*wave + c)*KSTR + d];
      #pragma unroll
      for (int n=0;n<4;++n) {
        s16x8 w_h = *(const s16x8*)&Whi[(16*n + c)*KSTR + d];
        s16x8 w_l = *(const s16x8*)&Wlo[(16*n + c)*KSTR + d];
        acc[n] = __builtin_amdgcn_mfma_f32_16x16x32_bf16(x_h, w_h, acc[n], 0, 0, 0);
        acc[n] = __builtin_amdgcn_mfma_f32_16x16x32_bf16(x_l, w_h, acc[n], 0, 0, 0);
        acc[n] = __builtin_amdgcn_mfma_f32_16x16x32_bf16(x_h, w_l, acc[n], 0, 0, 0);
        acc[n] = __builtin_amdgcn_mfma_f32_16x16x32_bf16(x_l, w_l, acc[n], 0, 0, 0);
      }
    }
  }

  #pragma unroll
  for (int r=0;r<4;++r) {
    const int row = m0 + 16*wave + 4*g + r;
    if (row >= NTOK) continue;
    const int b = row / S_LEN, s = row % S_LEN;
    #pragma unroll
    for (int n=0;n<4;++n) {
      const int cc = n0 + 16*n + c;
      const float v = acc[n][r];
      if (cc < 504) {
        int h = cc / 56, d = cc % 56;
        Qb[(((size_t)(b*NH+h))*S_LEN + s)*HD + d] = v;
      } else if (cc < 672) {
        int h = (cc-504)/56, d = (cc-504)%56;
        Kb[(((size_t)(b*NKV+h))*S_LEN + s)*HD + d] = v;
      } else if (cc < 864) {
        int h = (cc-672)/64, d = (cc-672)%64;
        Vb[(((size_t)(b*NKV+h))*S_LEN + s)*HD + d] = v;
      } else if (cc < 936) {
        int h = (cc-864)/8, d = 56 + (cc-864)%8;
        Qb[(((size_t)(b*NH+h))*S_LEN + s)*HD + d] = v;
      } else {
        int h = (cc-936)/8, d = 56 + (cc-936)%8;
        Kb[(((size_t)(b*NKV+h))*S_LEN + s)*HD + d] = v;
      }
    }
  }
}

// ---------------------------------------------------------------------------
// In-place partial RoPE on dims 56..63 of Q (9 heads) and K (3 heads).
// ---------------------------------------------------------------------------
__global__ void rope_kernel(float* __restrict__ Qb, float* __restrict__ Kb) {
  const int idx = blockIdx.x * blockDim.x + threadIdx.x;
  const int total = NB*(NH+NKV)*S_LEN;
  if (idx >= total) return;
  const int s  = idx % S_LEN;
  const int bh = idx / S_LEN;
  const int b  = bh / (NH+NKV), hh = bh % (NH+NKV);
  float* base;
  if (hh < NH) base = Qb + (((size_t)(b*NH + hh))*S_LEN + s)*HD + 56;
  else         base = Kb + (((size_t)(b*NKV + (hh-NH)))*S_LEN + s)*HD + 56;

  float4 a = *(const float4*)(base);
  float4 c = *(const float4*)(base + 4);
  float xv[8] = {a.x,a.y,a.z,a.w,c.x,c.y,c.z,c.w};
  const float es[4] = {0.0f, 2.0f/64.0f, 32.0f/64.0f, 34.0f/64.0f};
  const float ps = (float)s;
  float o[8];
  #pragma unroll
  for (int j=0;j<4;++j) {
    float th  = 1.0f / powf(100000.0f, es[j]);
    float ang = ps * th;
    float cs = cosf(ang), sn = sinf(ang);
    o[j]   = xv[j]*cs   - xv[j+4]*sn;
    o[j+4] = xv[j+4]*cs + xv[j]*sn;
  }
  *(float4*)(base)     = make_float4(o[0],o[1],o[2],o[3]);
  *(float4*)(base + 4) = make_float4(o[4],o[5],o[6],o[7]);
}

// ---------------------------------------------------------------------------
// 2-bit fake-quant of K (per 64-token group per dim, first 2048 tokens)
// ---------------------------------------------------------------------------
__global__ void quant_key_kernel(float* __restrict__ Kb) {
  const int wid  = (blockIdx.x * blockDim.x + threadIdx.x) >> 6;
  const int lane = threadIdx.x & 63;
  if (wid >= NB*NKV*32) return;
  const int bkh = wid >> 5, sg = wid & 31;
  float* base = Kb + ((size_t)bkh*S_LEN + sg*64)*HD + lane;
  float vals[64];
  float mn = 1e30f, mx = -1e30f;
  #pragma unroll
  for (int s=0;s<64;++s) {
    float v = fminf(fmaxf(base[s*HD], -10000.0f), 10000.0f);
    vals[s] = v;
    mn = fminf(mn, v); mx = fmaxf(mx, v);
  }
  float scale = (mx - mn) / 3.0f;
  if (scale == 0.0f) scale = 1.0f;
  #pragma unroll
  for (int s=0;s<64;++s) {
    float q = rintf((vals[s] - mn) / scale);
    base[s*HD] = q * scale + mn;
  }
}

// ---------------------------------------------------------------------------
// 2-bit fake-quant of V (per token over d=64, first 2032 tokens)
// ---------------------------------------------------------------------------
__global__ void quant_value_kernel(float* __restrict__ Vb) {
  const int wid  = (blockIdx.x * blockDim.x + threadIdx.x) >> 6;
  const int lane = threadIdx.x & 63;
  const int total = NB*NKV*2032;
  if (wid >= total) return;
  const int bkh = wid / 2032, s = wid % 2032;
  float* p = Vb + ((size_t)bkh*S_LEN + s)*HD + lane;
  float v = fminf(fmaxf(*p, -10000.0f), 10000.0f);
  float mn = v, mx = v;
  #pragma unroll
  for (int m=1;m<64;m<<=1) {
    mn = fminf(mn, __shfl_xor(mn, m));
    mx = fmaxf(mx, __shfl_xor(mx, m));
  }
  float scale = (mx - mn) / 3.0f;
  if (scale == 0.0f) scale = 1.0f;
  float q = rintf((v - mn) / scale);
  *p = q * scale + mn;
}

// ---------------------------------------------------------------------------
// Pack K (post-rope, post-quant) -> global bf16 hi/lo [bkv][S_PAD][64]
// ---------------------------------------------------------------------------
__global__ __launch_bounds__(256)
void pack_k_kernel(const float* __restrict__ Kb,
                   ushort* __restrict__ KhiG, ushort* __restrict__ KloG) {
  const int idx = blockIdx.x * blockDim.x + threadIdx.x;
  const int total = NB*NKV*S_PAD*8;
  if (idx >= total) return;
  const int bkv = idx / (S_PAD*8);
  const int rem = idx % (S_PAD*8);
  const int s = rem >> 3, d0 = (rem & 7) * 8;
  uint u_h[4], u_l[4];
  if (s < S_LEN) {
    const float* src = Kb + ((size_t)bkv*S_LEN + s)*HD + d0;
    float4 a = *(const float4*)(src);
    float4 b = *(const float4*)(src + 4);
    float v[8] = {a.x,a.y,a.z,a.w,b.x,b.y,b.z,b.w};
    ushort hb[8], lb[8];
    #pragma unroll
    for (int e=0;e<8;++e) {
      hb[e] = f2bf(v[e]);
      lb[e] = f2bf(v[e] - bf2f(hb[e]));
    }
    #pragma unroll
    for (int m=0;m<4;++m) {
      u_h[m] = (uint)hb[2*m] | ((uint)hb[2*m+1] << 16);
      u_l[m] = (uint)lb[2*m] | ((uint)lb[2*m+1] << 16);
    }
  } else {
    #pragma unroll
    for (int m=0;m<4;++m) { u_h[m] = 0; u_l[m] = 0; }
  }
  const size_t off = ((size_t)bkv*S_PAD + s)*HD + d0;
  *(uint4*)(KhiG + off) = make_uint4(u_h[0],u_h[1],u_h[2],u_h[3]);
  *(uint4*)(KloG + off) = make_uint4(u_l[0],u_l[1],u_l[2],u_l[3]);
}

// ---------------------------------------------------------------------------
// Pack V (post-quant) -> global TRANSPOSED bf16 (hi only) [bkv][64][S_PAD]
// ---------------------------------------------------------------------------
__global__ __launch_bounds__(256)
void pack_v_kernel(const float* __restrict__ Vb,
                   ushort* __restrict__ VhiT) {
  __shared__ float T[64*LSTR];     // [key][d]
  const int tid = threadIdx.x;
  const int bkv = blockIdx.x / 33;
  const int kt  = blockIdx.x % 33;
  const int kbase = kt * 64;

  {  // coalesced read of 64x64 f32 tile
    const int key = tid >> 2, c16 = (tid & 3) * 16;
    const int s = kbase + key;
    if (s < S_LEN) {
      const float* src = Vb + ((size_t)bkv*S_LEN + s)*HD + c16;
      #pragma unroll
      for (int i=0;i<4;++i) {
        float4 v = *(const float4*)(src + 4*i);
        *(float4*)(T + key*LSTR + c16 + 4*i) = v;
      }
    } else {
      #pragma unroll
      for (int i=0;i<4;++i)
        *(float4*)(T + key*LSTR + c16 + 4*i) = make_float4(0.f,0.f,0.f,0.f);
    }
  }
  __syncthreads();
  {  // write transposed rows (d-major), 16 keys per thread
    const int d = tid >> 2, seg = tid & 3;
    ushort hb[16];
    #pragma unroll
    for (int kk=0;kk<16;++kk)
      hb[kk] = f2bf(T[(seg*16 + kk)*LSTR + d]);
    uint uh[8];
    #pragma unroll
    for (int m=0;m<8;++m)
      uh[m] = (uint)hb[2*m] | ((uint)hb[2*m+1] << 16);
    const size_t off = ((size_t)bkv*HD + d)*S_PAD + kbase + seg*16;
    *(uint4*)(VhiT + off)     = make_uint4(uh[0],uh[1],uh[2],uh[3]);
    *(uint4*)(VhiT + off + 8) = make_uint4(uh[4],uh[5],uh[6],uh[7]);
  }
}

// ---------------------------------------------------------------------------
// Flash attention, split-K (flash-decoding style). Block (qt, bh, ch)
// processes k-tiles [CK*ch, min(CK*ch+CK, qt+1)). nch==1 -> write A directly;
// else write unnormalized partial O + per-row (m, l) for the reduce kernel.
// Structure identical to the measured R8 single-buffer kernel otherwise.
//   QK^T: 3-term split bf16 (f32-class logits); PV: plain bf16.
// LDS 36.9 KB -> 4 blocks/CU.
// ---------------------------------------------------------------------------
__global__ __launch_bounds__(256)
void attn_kernel(const float* __restrict__ Q,
                 const ushort* __restrict__ KhiG, const ushort* __restrict__ KloG,
                 const ushort* __restrict__ VhiT,
                 float* __restrict__ A,
                 float* __restrict__ Opart, float* __restrict__ Mpart,
                 float* __restrict__ Lpart, int CK) {
  __shared__ __align__(16) ushort Khi[64*KSTR];
  __shared__ __align__(16) ushort Klo[64*KSTR];
  __shared__ __align__(16) ushort Vhi[64*KSTR];
  __shared__ __align__(16) ushort Phi[64*KSTR];

  const int tid  = threadIdx.x;
  const int wave = tid >> 6;
  const int lane = tid & 63;
  const int g    = lane >> 4;      // k-group / row-group
  const int c    = lane & 15;      // col (B/D) / row (A) lane index

  const int qt = 32 - (int)blockIdx.x;     // heavy tiles first
  const int bh = blockIdx.y;
  const int ch = blockIdx.z;
  const int nch = (qt + CK) / CK;          // ceil((qt+1)/CK)
  if (ch >= nch) return;
  const int kt0 = ch * CK;
  const int kt1 = min(kt0 + CK, qt + 1);

  const int b = bh / NH, h = bh % NH, kvh = h / (NH/NKV);
  const int bkv = b*NKV + kvh;
  const float* Qg = Q + ((size_t)(b*NH + h)*S_LEN)*HD;
  const ushort* KhiB = KhiG + (size_t)bkv*S_PAD*HD;
  const ushort* KloB = KloG + (size_t)bkv*S_PAD*HD;
  const ushort* VhiB = VhiT + (size_t)bkv*HD*S_PAD;
  const int qbase = qt * 64;

  // ---- Q fragments (hi+lo split), A row = c
  s16x8 qhi[2], qlo[2];
  {
    int qrow = qbase + 16*wave + c;
    if (qrow > S_LEN-1) qrow = S_LEN-1;
    #pragma unroll
    for (int kc = 0; kc < 2; ++kc) {
      const float* qp = Qg + (size_t)qrow*HD + kc*32 + g*8;
      float4 q0 = *(const float4*)(qp);
      float4 q1 = *(const float4*)(qp + 4);
      float qv[8] = {q0.x,q0.y,q0.z,q0.w,q1.x,q1.y,q1.z,q1.w};
      #pragma unroll
      for (int e=0;e<8;++e) {
        ushort hi = f2bf(qv[e]);
        ushort lo = f2bf(qv[e] - bf2f(hi));
        qhi[kc][e] = (short)hi;
        qlo[kc][e] = (short)lo;
      }
    }
  }

  f32x4 acc_o[4];
  #pragma unroll
  for (int n=0;n<4;++n) acc_o[n] = (f32x4){0.f,0.f,0.f,0.f};
  float m_i[4], l_i[4];
  #pragma unroll
  for (int r=0;r<4;++r) { m_i[r] = -INFINITY; l_i[r] = 0.f; }

  // staging: thread t copies rows (t>>3) and (t>>3)+32, 8-elem seg (t&7)*8
  const int srow = tid >> 3;
  const int sseg = (tid & 7) * 8;

  for (int kt = kt0; kt < kt1; ++kt) {
    const int kbase = kt * 64;
    __syncthreads();   // all frag reads of prev tile done before restaging

    #pragma unroll
    for (int it=0; it<2; ++it) {
      const int r = srow + 32*it;
      const size_t kg = ((size_t)(kbase + r))*HD + sseg;
      *(uint4*)&Khi[r*KSTR + sseg] = *(const uint4*)(KhiB + kg);
      *(uint4*)&Klo[r*KSTR + sseg] = *(const uint4*)(KloB + kg);
      const size_t vg = (size_t)r*S_PAD + kbase + sseg;
      *(uint4*)&Vhi[r*KSTR + sseg] = *(const uint4*)(VhiB + vg);
    }
    __syncthreads();

    // ---- QK^T (split-3): sc[n] = 16x16 scores for keys [16n,16n+16)
    f32x4 sc[4];
    #pragma unroll
    for (int n=0;n<4;++n) sc[n] = (f32x4){0.f,0.f,0.f,0.f};
    #pragma unroll
    for (int kc=0; kc<2; ++kc) {
      #pragma unroll
      for (int n=0;n<4;++n) {
        const int key = 16*n + c;
        const int d   = kc*32 + g*8;
        s16x8 khf = *(const s16x8*)&Khi[key*KSTR + d];
        s16x8 klf = *(const s16x8*)&Klo[key*KSTR + d];
        sc[n] = __builtin_amdgcn_mfma_f32_16x16x32_bf16(qhi[kc], khf, sc[n], 0, 0, 0);
        sc[n] = __builtin_amdgcn_mfma_f32_16x16x32_bf16(qlo[kc], khf, sc[n], 0, 0, 0);
        sc[n] = __builtin_amdgcn_mfma_f32_16x16x32_bf16(qhi[kc], klf, sc[n], 0, 0, 0);
      }
    }

    // ---- online softmax. Lane holds rows 16w+4g+r, cols kbase+16n+c.
    const bool diag = (kt == qt);
    #pragma unroll
    for (int r=0;r<4;++r) {
      const int grow = qbase + 16*wave + 4*g + r;
      float s[4];
      #pragma unroll
      for (int n=0;n<4;++n) {
        float sv = sc[n][r] * 0.125f;
        if (diag && (kbase + 16*n + c > grow)) sv = -INFINITY;
        s[n] = sv;
      }
      float rm = fmaxf(fmaxf(s[0],s[1]), fmaxf(s[2],s[3]));
      rm = fmaxf(rm, __shfl_xor(rm, 1));
      rm = fmaxf(rm, __shfl_xor(rm, 2));
      rm = fmaxf(rm, __shfl_xor(rm, 4));
      rm = fmaxf(rm, __shfl_xor(rm, 8));
      const float mn = fmaxf(m_i[r], rm);
      const float al = __expf(m_i[r] - mn);   // exp(-inf)=0 on first tile
      float sum = 0.f;
      float pv4[4];
      #pragma unroll
      for (int n=0;n<4;++n) {
        float pv = __expf(s[n] - mn);
        pv4[n] = pv;
        sum += pv;
      }
      sum += __shfl_xor(sum, 1);
      sum += __shfl_xor(sum, 2);
      sum += __shfl_xor(sum, 4);
      sum += __shfl_xor(sum, 8);
      l_i[r] = l_i[r]*al + sum;
      m_i[r] = mn;
      #pragma unroll
      for (int n=0;n<4;++n) acc_o[n][r] *= al;
      // P rows are wave-private: no barrier needed
      #pragma unroll
      for (int n=0;n<4;++n)
        Phi[(16*wave + 4*g + r)*KSTR + 16*n + c] = f2bf(pv4[n]);
    }

    // ---- PV (plain bf16): O[16x64] += P[16x64] * V[64x64]
    #pragma unroll
    for (int kc=0; kc<2; ++kc) {
      const int pd = kc*32 + g*8;
      s16x8 pfh = *(const s16x8*)&Phi[(16*wave + c)*KSTR + pd];
      #pragma unroll
      for (int n=0;n<4;++n) {
        s16x8 vfh = *(const s16x8*)&Vhi[(16*n + c)*KSTR + pd];
        acc_o[n] = __builtin_amdgcn_mfma_f32_16x16x32_bf16(pfh, vfh, acc_o[n], 0, 0, 0);
      }
    }
  }

  if (nch == 1) {
    // single chunk: finalize directly into A (b, s, h*64+d)
    #pragma unroll
    for (int r=0;r<4;++r) {
      const int grow = qbase + 16*wave + 4*g + r;
      if (grow < S_LEN) {
        const float inv = 1.0f / l_i[r];
        #pragma unroll
        for (int n=0;n<4;++n)
          A[((size_t)(b*S_LEN + grow))*EMB + h*HD + 16*n + c] = acc_o[n][r] * inv;
      }
    }
  } else {
    // write unnormalized partial + (m, l)
    const int slot = bh*NSLOT_BH + cum8(qt) + ch;
    float* Ob = Opart + (size_t)slot * 4096;
    #pragma unroll
    for (int r=0;r<4;++r) {
      const int row = 16*wave + 4*g + r;
      #pragma unroll
      for (int n=0;n<4;++n)
        Ob[row*64 + 16*n + c] = acc_o[n][r];
      if (c == 0) {
        Mpart[(size_t)slot*64 + row] = m_i[r];
        Lpart[(size_t)slot*64 + row] = l_i[r];
      }
    }
  }
}

// ---------------------------------------------------------------------------
// Split-K reduce: for q-tiles with nch>=2 (qt>=8), merge partials:
//   M = max m_ch; L = sum l_ch e^{m_ch-M}; O = sum e^{m_ch-M} O_ch / L
// Block per (qt-8, bh); thread t -> row t>>2, col segment (t&3)*16.
// ---------------------------------------------------------------------------
__global__ __launch_bounds__(256)
void attn_reduce_kernel(const float* __restrict__ Opart,
                        const float* __restrict__ Mpart,
                        const float* __restrict__ Lpart,
                        float* __restrict__ A) {
  const int qt = 8 + (int)blockIdx.x;      // 8..32
  const int bh = blockIdx.y;
  const int b = bh / NH, h = bh % NH;
  const int nch = (qt + 8) / 8;
  const int base = bh*NSLOT_BH + cum8(qt);

  const int tid = threadIdx.x;
  const int row = tid >> 2;
  const int seg = (tid & 3) * 16;
  const int grow = qt*64 + row;
  if (grow >= S_LEN) return;

  float mv[5], lv[5];
  float M = -INFINITY;
  for (int ch=0; ch<nch; ++ch) {
    mv[ch] = Mpart[(size_t)(base+ch)*64 + row];
    lv[ch] = Lpart[(size_t)(base+ch)*64 + row];
    M = fmaxf(M, mv[ch]);
  }
  float L = 0.f;
  float w[5];
  for (int ch=0; ch<nch; ++ch) {
    w[ch] = __expf(mv[ch] - M);
    L += lv[ch] * w[ch];
  }
  float o[16];
  #pragma unroll
  for (int j=0;j<16;++j) o[j] = 0.f;
  for (int ch=0; ch<nch; ++ch) {
    const float* Ob = Opart + (size_t)(base+ch)*4096 + row*64 + seg;
    const float wc = w[ch];
    #pragma unroll
    for (int i=0;i<4;++i) {
      float4 v = *(const float4*)(Ob + 4*i);
      o[4*i+0] += wc*v.x; o[4*i+1] += wc*v.y;
      o[4*i+2] += wc*v.z; o[4*i+3] += wc*v.w;
    }
  }
  const float inv = 1.0f / L;
  float* dst = A + ((size_t)(b*S_LEN + grow))*EMB + h*HD + seg;
  #pragma unroll
  for (int i=0;i<4;++i)
    *(float4*)(dst + 4*i) = make_float4(o[4*i]*inv, o[4*i+1]*inv,
                                        o[4*i+2]*inv, o[4*i+3]*inv);
}

// ---------------------------------------------------------------------------
// Output projection via MFMA (split-bf16 3-term): out = A @ o_w^T
// ---------------------------------------------------------------------------
__global__ __launch_bounds__(256)
void oproj_kernel(const float* __restrict__ A, const float* __restrict__ ow,
                  float* __restrict__ out) {
  __shared__ __align__(16) ushort Ahi[64*KSTR];
  __shared__ __align__(16) ushort Alo[64*KSTR];
  __shared__ __align__(16) ushort Whi[64*KSTR];
  __shared__ __align__(16) ushort Wlo[64*KSTR];

  const int tid  = threadIdx.x;
  const int wave = tid >> 6;
  const int lane = tid & 63;
  const int g    = lane >> 4;
  const int c    = lane & 15;

  const int m0 = blockIdx.x * 64;
  const int n0 = blockIdx.y * 64;

  const int srow = tid >> 2;
  const int sseg = (tid & 3) * 16;
  int am = m0 + srow; if (am > NTOK-1) am = NTOK-1;
  const float* arow = A  + (size_t)am * EMB;
  const float* wrow = ow + (size_t)(n0 + srow) * EMB;   // always in-bounds (N=576)

  f32x4 acc[4];
  #pragma unroll
  for (int n=0;n<4;++n) acc[n] = (f32x4){0.f,0.f,0.f,0.f};

  for (int kc0 = 0; kc0 < EMB; kc0 += 64) {
    __syncthreads();
    {
      float av[16], wv[16];
      #pragma unroll
      for (int i=0;i<4;++i) {
        float4 a4 = *(const float4*)(arow + kc0 + sseg + 4*i);
        float4 w4 = *(const float4*)(wrow + kc0 + sseg + 4*i);
        av[4*i+0]=a4.x; av[4*i+1]=a4.y; av[4*i+2]=a4.z; av[4*i+3]=a4.w;
        wv[4*i+0]=w4.x; wv[4*i+1]=w4.y; wv[4*i+2]=w4.z; wv[4*i+3]=w4.w;
      }
      uint ah[8], al[8], wh[8], wl[8];
      #pragma unroll
      for (int m=0;m<8;++m) {
        ushort h0 = f2bf(av[2*m]),   h1 = f2bf(av[2*m+1]);
        ushort l0 = f2bf(av[2*m]   - bf2f(h0));
        ushort l1 = f2bf(av[2*m+1] - bf2f(h1));
        ah[m] = (uint)h0 | ((uint)h1 << 16);
        al[m] = (uint)l0 | ((uint)l1 << 16);
        ushort g0 = f2bf(wv[2*m]),   g1 = f2bf(wv[2*m+1]);
        ushort m0_ = f2bf(wv[2*m]   - bf2f(g0));
        ushort m1_ = f2bf(wv[2*m+1] - bf2f(g1));
        wh[m] = (uint)g0 | ((uint)g1 << 16);
        wl[m] = (uint)m0_ | ((uint)m1_ << 16);
      }
      const int lo = srow*KSTR + sseg;
      *(uint4*)&Ahi[lo]     = make_uint4(ah[0],ah[1],ah[2],ah[3]);
      *(uint4*)&Ahi[lo + 8] = make_uint4(ah[4],ah[5],ah[6],ah[7]);
      *(uint4*)&Alo[lo]     = make_uint4(al[0],al[1],al[2],al[3]);
      *(uint4*)&Alo[lo + 8] = make_uint4(al[4],al[5],al[6],al[7]);
      *(uint4*)&Whi[lo]     = make_uint4(wh[0],wh[1],wh[2],wh[3]);
      *(uint4*)&Whi[lo + 8] = make_uint4(wh[4],wh[5],wh[6],wh[7]);
      *(uint4*)&Wlo[lo]     = make_uint4(wl[0],wl[1],wl[2],wl[3]);
      *(uint4*)&Wlo[lo + 8] = make_uint4(wl[4],wl[5],wl[6],wl[7]);
    }
    __syncthreads();

    #pragma unroll
    for (int kc=0; kc<2; ++kc) {
      const int d = kc*32 + g*8;
      s16x8 a_h = *(const s16x8*)&Ahi[(16*wave + c)*KSTR + d];
      s16x8 a_l = *(const s16x8*)&Alo[(16*wave + c)*KSTR + d];
      #pragma unroll
      for (int n=0;n<4;++n) {
        s16x8 w_h = *(const s16x8*)&Whi[(16*n + c)*KSTR + d];
        s16x8 w_l = *(const s16x8*)&Wlo[(16*n + c)*KSTR + d];
        acc[n] = __builtin_amdgcn_mfma_f32_16x16x32_bf16(a_h, w_h, acc[n], 0, 0, 0);
        acc[n] = __builtin_amdgcn_mfma_f32_16x16x32_bf16(a_l, w_h, acc[n], 0, 0, 0);
        acc[n] = __builtin_amdgcn_mfma_f32_16x16x32_bf16(a_h, w_l, acc[n], 0, 0, 0);
      }
    }
  }

  #pragma unroll
  for (int r=0;r<4;++r) {
    const int m = m0 + 16*wave + 4*g + r;
    if (m < NTOK) {
      #pragma unroll
      for (int n=0;n<4;++n)
        out[(size_t)m*EMB + n0 + 16*n + c] = acc[n][r];
    }
  }
}

// ---------------------------------------------------------------------------
extern "C" void kernel_launch(void* const* d_in, const int* in_sizes, int n_in,
                              void* d_out, int out_size, void* d_ws, size_t ws_size,
                              hipStream_t stream) {
  const float* x   = (const float*)d_in[0];
  const float* qw  = (const float*)d_in[1];
  const float* kw  = (const float*)d_in[2];
  const float* vw  = (const float*)d_in[3];
  const float* qrw = (const float*)d_in[4];
  const float* krw = (const float*)d_in[5];
  const float* ow  = (const float*)d_in[6];
  float* out = (float*)d_out;

  float* ws = (float*)d_ws;
  float* Qb = ws;
  float* Kb = Qb + QSZ;
  float* Vb = Kb + KSZ;
  float* Ab = Vb + VSZ;
  ushort* KhiG = (ushort*)(Ab + ASZ);
  ushort* KloG = KhiG + KPK;
  ushort* VhiT = KloG + KPK;
  float* Opart = (float*)(VhiT + KPK);               // 1530 x 4096 f32
  float* Mpart = Opart + (size_t)NSLOTS*4096;        // 1530 x 64
  float* Lpart = Mpart + (size_t)NSLOTS*64;          // 1530 x 64

  const size_t need = (size_t)((char*)(Lpart + (size_t)NSLOTS*64) - (char*)d_ws);
  const bool splitk = (ws_size >= need);             // deterministic per-run

  // 1. fused projections (MFMA split-4)
  dim3 g1((NTOK + 63)/64, 960/64);            // 65 x 15
  proj_kernel<<<g1, 256, 0, stream>>>(x, qw, kw, vw, qrw, krw, Qb, Kb, Vb);

  // 2. rope on q_r / k_r
  {
    int total = NB*(NH+NKV)*S_LEN;
    rope_kernel<<<(total+255)/256, 256, 0, stream>>>(Qb, Kb);
  }

  // 3. fake-quant K (first 2048) and V (first 2032)
  {
    int kwaves = NB*NKV*32;
    quant_key_kernel<<<(kwaves*64+255)/256, 256, 0, stream>>>(Kb);
    int vwaves = NB*NKV*2032;
    quant_value_kernel<<<(vwaves*64+255)/256, 256, 0, stream>>>(Vb);
  }

  // 4. pack KV (K hi/lo row-major; V hi transposed), zero-padded
  {
    int ksegs = NB*NKV*S_PAD*8;
    pack_k_kernel<<<(ksegs+255)/256, 256, 0, stream>>>(Kb, KhiG, KloG);
    pack_v_kernel<<<NB*NKV*33, 256, 0, stream>>>(Vb, VhiT);
  }

  // 5. causal flash attention
  if (splitk) {
    dim3 ga(33, NB*NH, 5);                     // split-K: 1530 working blocks
    attn_kernel<<<ga, 256, 0, stream>>>(Qb, KhiG, KloG, VhiT, Ab,
                                        Opart, Mpart, Lpart, 8);
    dim3 gr(25, NB*NH);                        // merge qt>=8
    attn_reduce_kernel<<<gr, 256, 0, stream>>>(Opart, Mpart, Lpart, Ab);
  } else {
    dim3 ga(33, NB*NH, 1);                     // fallback = measured R8 path
    attn_kernel<<<ga, 256, 0, stream>>>(Qb, KhiG, KloG, VhiT, Ab,
                                        Opart, Mpart, Lpart, 33);
  }

  // 6. output projection (MFMA, split-bf16)
  dim3 go((NTOK + 63)/64, EMB/64);             // 65 x 9
  oproj_kernel<<<go, 256, 0, stream>>>(Ab, ow, out);
}

// Round 11
// 211.178 us; speedup vs baseline: 1.2684x; 1.0435x over previous
//
#include <hip/hip_runtime.h>
#include <math.h>

#define S_LEN 2064
#define S_PAD 2112               // 33 tiles * 64, zero-padded packed KV
#define NB 2
#define NH 9
#define NKV 3
#define HD 64
#define EMB 576
#define NTOK (NB*S_LEN)          // 4128
#define LSTR 68                  // padded f32 LDS stride
#define KSTR 72                  // bf16 LDS stride: 144B rows, 16B-aligned segs

#define QSZ (NB*NH*S_LEN*HD)     // 2377728
#define KSZ (NB*NKV*S_LEN*HD)    // 792576
#define VSZ (NB*NKV*S_LEN*HD)    // 792576
#define ASZ (NB*S_LEN*EMB)       // 2377728 (ushort count for Ahi/Alo)
#define KPK (NB*NKV*S_PAD*HD)    // 811008 (per packed buffer, ushorts)
#define WCAT (960*EMB)           // 552960
#define OWSZ (EMB*EMB)           // 331776

#define NSLOT_BH 77              // sum over qt>=8 of ceil((qt+1)/8)
#define NSLOTS (NB*NH*NSLOT_BH)  // 1386 partial slots (qt>=8 only)

typedef float  f32x4  __attribute__((ext_vector_type(4)));
typedef short  s16x8  __attribute__((ext_vector_type(8)));

// f32 <-> bf16 (RNE), bit-level
static __device__ __forceinline__ ushort f2bf(float x) {
  union { float f; unsigned u; } a; a.f = x;
  unsigned r = a.u + 0x7fffu + ((a.u >> 16) & 1u);
  return (ushort)(r >> 16);
}
static __device__ __forceinline__ float bf2f(ushort h) {
  union { unsigned u; float f; } a; a.u = ((unsigned)h) << 16;
  return a.f;
}
// cumulative chunk count before q-tile qt (CK=8): sum_{i=1..qt} ceil(i/8)
static __device__ __forceinline__ int cum8(int qt) {
  int a = qt >> 3, b = qt & 7;
  return (a + 1) * (4 * a + b);
}
static __device__ __forceinline__ void split8(const float* v, uint* uh, uint* ul) {
  ushort hb[8], lb[8];
  #pragma unroll
  for (int e=0;e<8;++e) {
    hb[e] = f2bf(v[e]);
    lb[e] = f2bf(v[e] - bf2f(hb[e]));
  }
  #pragma unroll
  for (int m=0;m<4;++m) {
    uh[m] = (uint)hb[2*m] | ((uint)hb[2*m+1] << 16);
    ul[m] = (uint)lb[2*m] | ((uint)lb[2*m+1] << 16);
  }
}

// ---------------------------------------------------------------------------
// Pre-split x, concatenated weights, and o_w into global bf16 hi/lo.
// One thread per 8-elem segment. Bit-identical to in-kernel splitting.
// ---------------------------------------------------------------------------
#define XSEG (NTOK*72)           // 297216
#define WSEG (960*72)            // 69120
#define OSEG (EMB*72)            // 41472
__global__ __launch_bounds__(256)
void pack_inputs_kernel(const float* __restrict__ x,
                        const float* __restrict__ qw, const float* __restrict__ kw,
                        const float* __restrict__ vw, const float* __restrict__ qrw,
                        const float* __restrict__ krw, const float* __restrict__ ow,
                        ushort* __restrict__ XhiG, ushort* __restrict__ XloG,
                        ushort* __restrict__ WcatHi, ushort* __restrict__ WcatLo,
                        ushort* __restrict__ OWhi, ushort* __restrict__ OWlo) {
  const int idx = blockIdx.x * blockDim.x + threadIdx.x;
  if (idx >= XSEG + WSEG + OSEG) return;
  const float* src;
  ushort *dh, *dl;
  if (idx < XSEG) {
    const int row = idx / 72, seg = (idx % 72) * 8;
    src = x + (size_t)row*EMB + seg;
    dh = XhiG + (size_t)row*EMB + seg;
    dl = XloG + (size_t)row*EMB + seg;
  } else if (idx < XSEG + WSEG) {
    const int j = idx - XSEG;
    const int col = j / 72, seg = (j % 72) * 8;
    const float* wrow;
    if (col < 504)      wrow = qw  + (size_t)col       * EMB;
    else if (col < 672) wrow = kw  + (size_t)(col-504) * EMB;
    else if (col < 864) wrow = vw  + (size_t)(col-672) * EMB;
    else if (col < 936) wrow = qrw + (size_t)(col-864) * EMB;
    else                wrow = krw + (size_t)(col-936) * EMB;
    src = wrow + seg;
    dh = WcatHi + (size_t)col*EMB + seg;
    dl = WcatLo + (size_t)col*EMB + seg;
  } else {
    const int j = idx - XSEG - WSEG;
    const int row = j / 72, seg = (j % 72) * 8;
    src = ow + (size_t)row*EMB + seg;
    dh = OWhi + (size_t)row*EMB + seg;
    dl = OWlo + (size_t)row*EMB + seg;
  }
  float4 a = *(const float4*)(src);
  float4 b = *(const float4*)(src + 4);
  float v[8] = {a.x,a.y,a.z,a.w,b.x,b.y,b.z,b.w};
  uint uh[4], ul[4];
  split8(v, uh, ul);
  *(uint4*)dh = make_uint4(uh[0],uh[1],uh[2],uh[3]);
  *(uint4*)dl = make_uint4(ul[0],ul[1],ul[2],ul[3]);
}

// ---------------------------------------------------------------------------
// Fused QKV/Qr/Kr projection via MFMA, split-4 bf16. Staging = pure copies
// from pre-packed X/Wcat. Scatter epilogue unchanged (bit-identical output).
// ---------------------------------------------------------------------------
__global__ __launch_bounds__(256)
void proj_kernel(const ushort* __restrict__ XhiG, const ushort* __restrict__ XloG,
                 const ushort* __restrict__ WcatHi, const ushort* __restrict__ WcatLo,
                 float* __restrict__ Qb, float* __restrict__ Kb,
                 float* __restrict__ Vb) {
  __shared__ __align__(16) ushort Xhi[64*KSTR];
  __shared__ __align__(16) ushort Xlo[64*KSTR];
  __shared__ __align__(16) ushort Whi[64*KSTR];
  __shared__ __align__(16) ushort Wlo[64*KSTR];

  const int tid  = threadIdx.x;
  const int wave = tid >> 6;
  const int lane = tid & 63;
  const int g    = lane >> 4;
  const int c    = lane & 15;

  const int m0 = blockIdx.x * 64;
  const int n0 = blockIdx.y * 64;

  const int srow = tid >> 2;
  const int sseg = (tid & 3) * 16;
  int gm = m0 + srow; if (gm > NTOK-1) gm = NTOK-1;
  const ushort* xh = XhiG + (size_t)gm*EMB;
  const ushort* xl = XloG + (size_t)gm*EMB;
  const ushort* wh = WcatHi + (size_t)(n0 + srow)*EMB;
  const ushort* wl = WcatLo + (size_t)(n0 + srow)*EMB;

  f32x4 acc[4];
  #pragma unroll
  for (int n=0;n<4;++n) acc[n] = (f32x4){0.f,0.f,0.f,0.f};

  for (int kc0 = 0; kc0 < EMB; kc0 += 64) {
    __syncthreads();
    {
      const int go = kc0 + sseg;
      const int lo = srow*KSTR + sseg;
      *(uint4*)&Xhi[lo]     = *(const uint4*)(xh + go);
      *(uint4*)&Xhi[lo + 8] = *(const uint4*)(xh + go + 8);
      *(uint4*)&Xlo[lo]     = *(const uint4*)(xl + go);
      *(uint4*)&Xlo[lo + 8] = *(const uint4*)(xl + go + 8);
      *(uint4*)&Whi[lo]     = *(const uint4*)(wh + go);
      *(uint4*)&Whi[lo + 8] = *(const uint4*)(wh + go + 8);
      *(uint4*)&Wlo[lo]     = *(const uint4*)(wl + go);
      *(uint4*)&Wlo[lo + 8] = *(const uint4*)(wl + go + 8);
    }
    __syncthreads();

    #pragma unroll
    for (int kc=0; kc<2; ++kc) {
      const int d = kc*32 + g*8;
      s16x8 x_h = *(const s16x8*)&Xhi[(16*wave + c)*KSTR + d];
      s16x8 x_l = *(const s16x8*)&Xlo[(16*wave + c)*KSTR + d];
      #pragma unroll
      for (int n=0;n<4;++n) {
        s16x8 w_h = *(const s16x8*)&Whi[(16*n + c)*KSTR + d];
        s16x8 w_l = *(const s16x8*)&Wlo[(16*n + c)*KSTR + d];
        acc[n] = __builtin_amdgcn_mfma_f32_16x16x32_bf16(x_h, w_h, acc[n], 0, 0, 0);
        acc[n] = __builtin_amdgcn_mfma_f32_16x16x32_bf16(x_l, w_h, acc[n], 0, 0, 0);
        acc[n] = __builtin_amdgcn_mfma_f32_16x16x32_bf16(x_h, w_l, acc[n], 0, 0, 0);
        acc[n] = __builtin_amdgcn_mfma_f32_16x16x32_bf16(x_l, w_l, acc[n], 0, 0, 0);
      }
    }
  }

  #pragma unroll
  for (int r=0;r<4;++r) {
    const int row = m0 + 16*wave + 4*g + r;
    if (row >= NTOK) continue;
    const int b = row / S_LEN, s = row % S_LEN;
    #pragma unroll
    for (int n=0;n<4;++n) {
      const int cc = n0 + 16*n + c;
      const float v = acc[n][r];
      if (cc < 504) {
        int h = cc / 56, d = cc % 56;
        Qb[(((size_t)(b*NH+h))*S_LEN + s)*HD + d] = v;
      } else if (cc < 672) {
        int h = (cc-504)/56, d = (cc-504)%56;
        Kb[(((size_t)(b*NKV+h))*S_LEN + s)*HD + d] = v;
      } else if (cc < 864) {
        int h = (cc-672)/64, d = (cc-672)%64;
        Vb[(((size_t)(b*NKV+h))*S_LEN + s)*HD + d] = v;
      } else if (cc < 936) {
        int h = (cc-864)/8, d = 56 + (cc-864)%8;
        Qb[(((size_t)(b*NH+h))*S_LEN + s)*HD + d] = v;
      } else {
        int h = (cc-936)/8, d = 56 + (cc-936)%8;
        Kb[(((size_t)(b*NKV+h))*S_LEN + s)*HD + d] = v;
      }
    }
  }
}

// ---------------------------------------------------------------------------
// In-place partial RoPE on dims 56..63 of Q (9 heads) and K (3 heads).
// ---------------------------------------------------------------------------
__global__ void rope_kernel(float* __restrict__ Qb, float* __restrict__ Kb) {
  const int idx = blockIdx.x * blockDim.x + threadIdx.x;
  const int total = NB*(NH+NKV)*S_LEN;
  if (idx >= total) return;
  const int s  = idx % S_LEN;
  const int bh = idx / S_LEN;
  const int b  = bh / (NH+NKV), hh = bh % (NH+NKV);
  float* base;
  if (hh < NH) base = Qb + (((size_t)(b*NH + hh))*S_LEN + s)*HD + 56;
  else         base = Kb + (((size_t)(b*NKV + (hh-NH)))*S_LEN + s)*HD + 56;

  float4 a = *(const float4*)(base);
  float4 c = *(const float4*)(base + 4);
  float xv[8] = {a.x,a.y,a.z,a.w,c.x,c.y,c.z,c.w};
  const float es[4] = {0.0f, 2.0f/64.0f, 32.0f/64.0f, 34.0f/64.0f};
  const float ps = (float)s;
  float o[8];
  #pragma unroll
  for (int j=0;j<4;++j) {
    float th  = 1.0f / powf(100000.0f, es[j]);
    float ang = ps * th;
    float cs = cosf(ang), sn = sinf(ang);
    o[j]   = xv[j]*cs   - xv[j+4]*sn;
    o[j+4] = xv[j+4]*cs + xv[j]*sn;
  }
  *(float4*)(base)     = make_float4(o[0],o[1],o[2],o[3]);
  *(float4*)(base + 4) = make_float4(o[4],o[5],o[6],o[7]);
}

// ---------------------------------------------------------------------------
// Fused 2-bit fake-quant + pack for K. Block per (bkv, 64-key tile).
// Tile == one quant group (GROUP=64 consecutive tokens). kt==32 -> raw tail
// rows 2048..2063 (no clip, no quant), zero rows >= S_LEN.
// Output: bf16 hi/lo [bkv][S_PAD][64].
// ---------------------------------------------------------------------------
__global__ __launch_bounds__(256)
void packqk_kernel(const float* __restrict__ Kb,
                   ushort* __restrict__ KhiG, ushort* __restrict__ KloG) {
  __shared__ float T[64*LSTR];
  __shared__ float PMN[4][64], PMX[4][64];
  __shared__ float MN[64], SC[64];
  const int tid = threadIdx.x;
  const int bkv = blockIdx.x / 33;
  const int kt  = blockIdx.x % 33;
  const int kbase = kt * 64;

  {  // load 64x64 f32 tile (zero-padded)
    const int r = tid >> 2, c16 = (tid & 3) * 16;
    const int s = kbase + r;
    if (s < S_LEN) {
      const float* src = Kb + ((size_t)bkv*S_LEN + s)*HD + c16;
      #pragma unroll
      for (int i=0;i<4;++i)
        *(float4*)(T + r*LSTR + c16 + 4*i) = *(const float4*)(src + 4*i);
    } else {
      #pragma unroll
      for (int i=0;i<4;++i)
        *(float4*)(T + r*LSTR + c16 + 4*i) = make_float4(0.f,0.f,0.f,0.f);
    }
  }
  __syncthreads();

  if (kt < 32) {      // quant group: per-dim min/max over 64 tokens (clipped)
    const int d = tid & 63, q = tid >> 6;
    float mn = 1e30f, mx = -1e30f;
    #pragma unroll
    for (int i=0;i<16;++i) {
      float v = fminf(fmaxf(T[(16*q + i)*LSTR + d], -10000.0f), 10000.0f);
      mn = fminf(mn, v); mx = fmaxf(mx, v);
    }
    PMN[q][d] = mn; PMX[q][d] = mx;
    __syncthreads();
    if (tid < 64) {
      float m0 = fminf(fminf(PMN[0][tid],PMN[1][tid]), fminf(PMN[2][tid],PMN[3][tid]));
      float m1 = fmaxf(fmaxf(PMX[0][tid],PMX[1][tid]), fmaxf(PMX[2][tid],PMX[3][tid]));
      float sc = (m1 - m0) / 3.0f;
      if (sc == 0.0f) sc = 1.0f;
      MN[tid] = m0; SC[tid] = sc;
    }
    __syncthreads();
  }

  {  // quantize (if kt<32) + pack hi/lo
    const int r = tid >> 2, c16 = (tid & 3) * 16;
    float v16[16];
    #pragma unroll
    for (int j=0;j<16;++j) {
      const int d = c16 + j;
      float v = T[r*LSTR + d];
      if (kt < 32) {
        v = fminf(fmaxf(v, -10000.0f), 10000.0f);
        v = rintf((v - MN[d]) / SC[d]) * SC[d] + MN[d];
      }
      v16[j] = v;
    }
    uint uh[8], ul[8];
    split8(v16,     uh,     ul);
    split8(v16 + 8, uh + 4, ul + 4);
    const size_t off = ((size_t)bkv*S_PAD + kbase + r)*HD + c16;
    *(uint4*)(KhiG + off)     = make_uint4(uh[0],uh[1],uh[2],uh[3]);
    *(uint4*)(KhiG + off + 8) = make_uint4(uh[4],uh[5],uh[6],uh[7]);
    *(uint4*)(KloG + off)     = make_uint4(ul[0],ul[1],ul[2],ul[3]);
    *(uint4*)(KloG + off + 8) = make_uint4(ul[4],ul[5],ul[6],ul[7]);
  }
}

// ---------------------------------------------------------------------------
// Fused 2-bit fake-quant + transpose-pack for V. Block per (bkv, tile).
// Per-token (row) min/max over d=64; quant only rows s<2032 (clip+deq);
// raw rows 2032..2063; zero rows >= S_LEN. Output bf16 hi [bkv][64][S_PAD].
// ---------------------------------------------------------------------------
__global__ __launch_bounds__(256)
void packqv_kernel(const float* __restrict__ Vb,
                   ushort* __restrict__ VhiT) {
  __shared__ float T[64*LSTR];
  __shared__ float PMN[4][64], PMX[4][64];
  __shared__ float MN[64], SC[64];
  const int tid = threadIdx.x;
  const int bkv = blockIdx.x / 33;
  const int kt  = blockIdx.x % 33;
  const int kbase = kt * 64;

  {  // load
    const int r = tid >> 2, c16 = (tid & 3) * 16;
    const int s = kbase + r;
    if (s < S_LEN) {
      const float* src = Vb + ((size_t)bkv*S_LEN + s)*HD + c16;
      #pragma unroll
      for (int i=0;i<4;++i)
        *(float4*)(T + r*LSTR + c16 + 4*i) = *(const float4*)(src + 4*i);
    } else {
      #pragma unroll
      for (int i=0;i<4;++i)
        *(float4*)(T + r*LSTR + c16 + 4*i) = make_float4(0.f,0.f,0.f,0.f);
    }
  }
  __syncthreads();

  {  // per-row min/max over d (clipped)
    const int r = tid & 63, q = tid >> 6;
    float mn = 1e30f, mx = -1e30f;
    #pragma unroll
    for (int i=0;i<16;++i) {
      float v = fminf(fmaxf(T[r*LSTR + 16*q + i], -10000.0f), 10000.0f);
      mn = fminf(mn, v); mx = fmaxf(mx, v);
    }
    PMN[q][r] = mn; PMX[q][r] = mx;
  }
  __syncthreads();
  if (tid < 64) {
    float m0 = fminf(fminf(PMN[0][tid],PMN[1][tid]), fminf(PMN[2][tid],PMN[3][tid]));
    float m1 = fmaxf(fmaxf(PMX[0][tid],PMX[1][tid]), fmaxf(PMX[2][tid],PMX[3][tid]));
    float sc = (m1 - m0) / 3.0f;
    if (sc == 0.0f) sc = 1.0f;
    MN[tid] = m0; SC[tid] = sc;
  }
  __syncthreads();

  {  // transpose-pack: thread -> dim d, 16 keys
    const int d = tid >> 2, seg = tid & 3;
    ushort hb[16];
    #pragma unroll
    for (int j=0;j<16;++j) {
      const int k = 16*seg + j;
      float v = T[k*LSTR + d];
      if (kbase + k < 2032) {
        v = fminf(fmaxf(v, -10000.0f), 10000.0f);
        v = rintf((v - MN[k]) / SC[k]) * SC[k] + MN[k];
      }
      hb[j] = f2bf(v);
    }
    uint uh[8];
    #pragma unroll
    for (int m=0;m<8;++m)
      uh[m] = (uint)hb[2*m] | ((uint)hb[2*m+1] << 16);
    const size_t off = ((size_t)bkv*HD + d)*S_PAD + kbase + seg*16;
    *(uint4*)(VhiT + off)     = make_uint4(uh[0],uh[1],uh[2],uh[3]);
    *(uint4*)(VhiT + off + 8) = make_uint4(uh[4],uh[5],uh[6],uh[7]);
  }
}

// ---------------------------------------------------------------------------
// Flash attention, split-K. Block (qt, bh, ch) processes k-tiles
// [CK*ch, min(CK*ch+CK, qt+1)). nch==1 -> write packed A directly; else
// write unnormalized partial O + (m,l). QK split-3 bf16; PV plain bf16.
// ---------------------------------------------------------------------------
__global__ __launch_bounds__(256)
void attn_kernel(const float* __restrict__ Q,
                 const ushort* __restrict__ KhiG, const ushort* __restrict__ KloG,
                 const ushort* __restrict__ VhiT,
                 ushort* __restrict__ AhiG, ushort* __restrict__ AloG,
                 float* __restrict__ Opart, float* __restrict__ Mpart,
                 float* __restrict__ Lpart, int CK) {
  __shared__ __align__(16) ushort Khi[64*KSTR];
  __shared__ __align__(16) ushort Klo[64*KSTR];
  __shared__ __align__(16) ushort Vhi[64*KSTR];
  __shared__ __align__(16) ushort Phi[64*KSTR];

  const int tid  = threadIdx.x;
  const int wave = tid >> 6;
  const int lane = tid & 63;
  const int g    = lane >> 4;
  const int c    = lane & 15;

  const int qt = 32 - (int)blockIdx.x;
  const int bh = blockIdx.y;
  const int ch = blockIdx.z;
  const int nch = (qt + CK) / CK;
  if (ch >= nch) return;
  const int kt0 = ch * CK;
  const int kt1 = min(kt0 + CK, qt + 1);

  const int b = bh / NH, h = bh % NH, kvh = h / (NH/NKV);
  const int bkv = b*NKV + kvh;
  const float* Qg = Q + ((size_t)(b*NH + h)*S_LEN)*HD;
  const ushort* KhiB = KhiG + (size_t)bkv*S_PAD*HD;
  const ushort* KloB = KloG + (size_t)bkv*S_PAD*HD;
  const ushort* VhiB = VhiT + (size_t)bkv*HD*S_PAD;
  const int qbase = qt * 64;

  s16x8 qhi[2], qlo[2];
  {
    int qrow = qbase + 16*wave + c;
    if (qrow > S_LEN-1) qrow = S_LEN-1;
    #pragma unroll
    for (int kc = 0; kc < 2; ++kc) {
      const float* qp = Qg + (size_t)qrow*HD + kc*32 + g*8;
      float4 q0 = *(const float4*)(qp);
      float4 q1 = *(const float4*)(qp + 4);
      float qv[8] = {q0.x,q0.y,q0.z,q0.w,q1.x,q1.y,q1.z,q1.w};
      #pragma unroll
      for (int e=0;e<8;++e) {
        ushort hi = f2bf(qv[e]);
        ushort lo = f2bf(qv[e] - bf2f(hi));
        qhi[kc][e] = (short)hi;
        qlo[kc][e] = (short)lo;
      }
    }
  }

  f32x4 acc_o[4];
  #pragma unroll
  for (int n=0;n<4;++n) acc_o[n] = (f32x4){0.f,0.f,0.f,0.f};
  float m_i[4], l_i[4];
  #pragma unroll
  for (int r=0;r<4;++r) { m_i[r] = -INFINITY; l_i[r] = 0.f; }

  const int srow = tid >> 3;
  const int sseg = (tid & 7) * 8;

  for (int kt = kt0; kt < kt1; ++kt) {
    const int kbase = kt * 64;
    __syncthreads();

    #pragma unroll
    for (int it=0; it<2; ++it) {
      const int r = srow + 32*it;
      const size_t kg = ((size_t)(kbase + r))*HD + sseg;
      *(uint4*)&Khi[r*KSTR + sseg] = *(const uint4*)(KhiB + kg);
      *(uint4*)&Klo[r*KSTR + sseg] = *(const uint4*)(KloB + kg);
      const size_t vg = (size_t)r*S_PAD + kbase + sseg;
      *(uint4*)&Vhi[r*KSTR + sseg] = *(const uint4*)(VhiB + vg);
    }
    __syncthreads();

    f32x4 sc[4];
    #pragma unroll
    for (int n=0;n<4;++n) sc[n] = (f32x4){0.f,0.f,0.f,0.f};
    #pragma unroll
    for (int kc=0; kc<2; ++kc) {
      #pragma unroll
      for (int n=0;n<4;++n) {
        const int key = 16*n + c;
        const int d   = kc*32 + g*8;
        s16x8 khf = *(const s16x8*)&Khi[key*KSTR + d];
        s16x8 klf = *(const s16x8*)&Klo[key*KSTR + d];
        sc[n] = __builtin_amdgcn_mfma_f32_16x16x32_bf16(qhi[kc], khf, sc[n], 0, 0, 0);
        sc[n] = __builtin_amdgcn_mfma_f32_16x16x32_bf16(qlo[kc], khf, sc[n], 0, 0, 0);
        sc[n] = __builtin_amdgcn_mfma_f32_16x16x32_bf16(qhi[kc], klf, sc[n], 0, 0, 0);
      }
    }

    const bool diag = (kt == qt);
    #pragma unroll
    for (int r=0;r<4;++r) {
      const int grow = qbase + 16*wave + 4*g + r;
      float s[4];
      #pragma unroll
      for (int n=0;n<4;++n) {
        float sv = sc[n][r] * 0.125f;
        if (diag && (kbase + 16*n + c > grow)) sv = -INFINITY;
        s[n] = sv;
      }
      float rm = fmaxf(fmaxf(s[0],s[1]), fmaxf(s[2],s[3]));
      rm = fmaxf(rm, __shfl_xor(rm, 1));
      rm = fmaxf(rm, __shfl_xor(rm, 2));
      rm = fmaxf(rm, __shfl_xor(rm, 4));
      rm = fmaxf(rm, __shfl_xor(rm, 8));
      const float mn = fmaxf(m_i[r], rm);
      const float al = __expf(m_i[r] - mn);
      float sum = 0.f;
      float pv4[4];
      #pragma unroll
      for (int n=0;n<4;++n) {
        float pv = __expf(s[n] - mn);
        pv4[n] = pv;
        sum += pv;
      }
      sum += __shfl_xor(sum, 1);
      sum += __shfl_xor(sum, 2);
      sum += __shfl_xor(sum, 4);
      sum += __shfl_xor(sum, 8);
      l_i[r] = l_i[r]*al + sum;
      m_i[r] = mn;
      #pragma unroll
      for (int n=0;n<4;++n) acc_o[n][r] *= al;
      #pragma unroll
      for (int n=0;n<4;++n)
        Phi[(16*wave + 4*g + r)*KSTR + 16*n + c] = f2bf(pv4[n]);
    }

    #pragma unroll
    for (int kc=0; kc<2; ++kc) {
      const int pd = kc*32 + g*8;
      s16x8 pfh = *(const s16x8*)&Phi[(16*wave + c)*KSTR + pd];
      #pragma unroll
      for (int n=0;n<4;++n) {
        s16x8 vfh = *(const s16x8*)&Vhi[(16*n + c)*KSTR + pd];
        acc_o[n] = __builtin_amdgcn_mfma_f32_16x16x32_bf16(pfh, vfh, acc_o[n], 0, 0, 0);
      }
    }
  }

  if (nch == 1) {
    // finalize directly into packed A (hi/lo split == oproj's old in-kernel split)
    #pragma unroll
    for (int r=0;r<4;++r) {
      const int grow = qbase + 16*wave + 4*g + r;
      if (grow < S_LEN) {
        const float inv = 1.0f / l_i[r];
        const size_t base = ((size_t)(b*S_LEN + grow))*EMB + h*HD;
        #pragma unroll
        for (int n=0;n<4;++n) {
          float v = acc_o[n][r] * inv;
          ushort hh = f2bf(v);
          AhiG[base + 16*n + c] = hh;
          AloG[base + 16*n + c] = f2bf(v - bf2f(hh));
        }
      }
    }
  } else {
    const int slot = bh*NSLOT_BH + (cum8(qt) - 8) + ch;
    float* Ob = Opart + (size_t)slot * 4096;
    #pragma unroll
    for (int r=0;r<4;++r) {
      const int row = 16*wave + 4*g + r;
      #pragma unroll
      for (int n=0;n<4;++n)
        Ob[row*64 + 16*n + c] = acc_o[n][r];
      if (c == 0) {
        Mpart[(size_t)slot*64 + row] = m_i[r];
        Lpart[(size_t)slot*64 + row] = l_i[r];
      }
    }
  }
}

// ---------------------------------------------------------------------------
// Split-K reduce (qt>=8): merge partials, write packed A hi/lo.
// ---------------------------------------------------------------------------
__global__ __launch_bounds__(256)
void attn_reduce_kernel(const float* __restrict__ Opart,
                        const float* __restrict__ Mpart,
                        const float* __restrict__ Lpart,
                        ushort* __restrict__ AhiG, ushort* __restrict__ AloG) {
  const int qt = 8 + (int)blockIdx.x;      // 8..32
  const int bh = blockIdx.y;
  const int b = bh / NH, h = bh % NH;
  const int nch = (qt + 8) / 8;
  const int base = bh*NSLOT_BH + (cum8(qt) - 8);

  const int tid = threadIdx.x;
  const int row = tid >> 2;
  const int seg = (tid & 3) * 16;
  const int grow = qt*64 + row;
  if (grow >= S_LEN) return;

  float mv[5], lv[5];
  float M = -INFINITY;
  for (int ch=0; ch<nch; ++ch) {
    mv[ch] = Mpart[(size_t)(base+ch)*64 + row];
    lv[ch] = Lpart[(size_t)(base+ch)*64 + row];
    M = fmaxf(M, mv[ch]);
  }
  float L = 0.f;
  float w[5];
  for (int ch=0; ch<nch; ++ch) {
    w[ch] = __expf(mv[ch] - M);
    L += lv[ch] * w[ch];
  }
  float o[16];
  #pragma unroll
  for (int j=0;j<16;++j) o[j] = 0.f;
  for (int ch=0; ch<nch; ++ch) {
    const float* Ob = Opart + (size_t)(base+ch)*4096 + row*64 + seg;
    const float wc = w[ch];
    #pragma unroll
    for (int i=0;i<4;++i) {
      float4 v = *(const float4*)(Ob + 4*i);
      o[4*i+0] += wc*v.x; o[4*i+1] += wc*v.y;
      o[4*i+2] += wc*v.z; o[4*i+3] += wc*v.w;
    }
  }
  const float inv = 1.0f / L;
  float v16[16];
  #pragma unroll
  for (int j=0;j<16;++j) v16[j] = o[j]*inv;
  uint uh[8], ul[8];
  split8(v16,     uh,     ul);
  split8(v16 + 8, uh + 4, ul + 4);
  const size_t dst = ((size_t)(b*S_LEN + grow))*EMB + h*HD + seg;
  *(uint4*)(AhiG + dst)     = make_uint4(uh[0],uh[1],uh[2],uh[3]);
  *(uint4*)(AhiG + dst + 8) = make_uint4(uh[4],uh[5],uh[6],uh[7]);
  *(uint4*)(AloG + dst)     = make_uint4(ul[0],ul[1],ul[2],ul[3]);
  *(uint4*)(AloG + dst + 8) = make_uint4(ul[4],ul[5],ul[6],ul[7]);
}

// ---------------------------------------------------------------------------
// Output projection via MFMA (split-3): out = A @ o_w^T. Pure-copy staging
// from pre-packed A and OW (bit-identical to R10's in-kernel split).
// ---------------------------------------------------------------------------
__global__ __launch_bounds__(256)
void oproj_kernel(const ushort* __restrict__ AhiG, const ushort* __restrict__ AloG,
                  const ushort* __restrict__ OWhi, const ushort* __restrict__ OWlo,
                  float* __restrict__ out) {
  __shared__ __align__(16) ushort Ahi[64*KSTR];
  __shared__ __align__(16) ushort Alo[64*KSTR];
  __shared__ __align__(16) ushort Whi[64*KSTR];
  __shared__ __align__(16) ushort Wlo[64*KSTR];

  const int tid  = threadIdx.x;
  const int wave = tid >> 6;
  const int lane = tid & 63;
  const int g    = lane >> 4;
  const int c    = lane & 15;

  const int m0 = blockIdx.x * 64;
  const int n0 = blockIdx.y * 64;

  const int srow = tid >> 2;
  const int sseg = (tid & 3) * 16;
  int am = m0 + srow; if (am > NTOK-1) am = NTOK-1;
  const ushort* ah = AhiG + (size_t)am*EMB;
  const ushort* al = AloG + (size_t)am*EMB;
  const ushort* wh = OWhi + (size_t)(n0 + srow)*EMB;
  const ushort* wl = OWlo + (size_t)(n0 + srow)*EMB;

  f32x4 acc[4];
  #pragma unroll
  for (int n=0;n<4;++n) acc[n] = (f32x4){0.f,0.f,0.f,0.f};

  for (int kc0 = 0; kc0 < EMB; kc0 += 64) {
    __syncthreads();
    {
      const int go = kc0 + sseg;
      const int lo = srow*KSTR + sseg;
      *(uint4*)&Ahi[lo]     = *(const uint4*)(ah + go);
      *(uint4*)&Ahi[lo + 8] = *(const uint4*)(ah + go + 8);
      *(uint4*)&Alo[lo]     = *(const uint4*)(al + go);
      *(uint4*)&Alo[lo + 8] = *(const uint4*)(al + go + 8);
      *(uint4*)&Whi[lo]     = *(const uint4*)(wh + go);
      *(uint4*)&Whi[lo + 8] = *(const uint4*)(wh + go + 8);
      *(uint4*)&Wlo[lo]     = *(const uint4*)(wl + go);
      *(uint4*)&Wlo[lo + 8] = *(const uint4*)(wl + go + 8);
    }
    __syncthreads();

    #pragma unroll
    for (int kc=0; kc<2; ++kc) {
      const int d = kc*32 + g*8;
      s16x8 a_h = *(const s16x8*)&Ahi[(16*wave + c)*KSTR + d];
      s16x8 a_l = *(const s16x8*)&Alo[(16*wave + c)*KSTR + d];
      #pragma unroll
      for (int n=0;n<4;++n) {
        s16x8 w_h = *(const s16x8*)&Whi[(16*n + c)*KSTR + d];
        s16x8 w_l = *(const s16x8*)&Wlo[(16*n + c)*KSTR + d];
        acc[n] = __builtin_amdgcn_mfma_f32_16x16x32_bf16(a_h, w_h, acc[n], 0, 0, 0);
        acc[n] = __builtin_amdgcn_mfma_f32_16x16x32_bf16(a_l, w_h, acc[n], 0, 0, 0);
        acc[n] = __builtin_amdgcn_mfma_f32_16x16x32_bf16(a_h, w_l, acc[n], 0, 0, 0);
      }
    }
  }

  #pragma unroll
  for (int r=0;r<4;++r) {
    const int m = m0 + 16*wave + 4*g + r;
    if (m < NTOK) {
      #pragma unroll
      for (int n=0;n<4;++n)
        out[(size_t)m*EMB + n0 + 16*n + c] = acc[n][r];
    }
  }
}

// ---------------------------------------------------------------------------
extern "C" void kernel_launch(void* const* d_in, const int* in_sizes, int n_in,
                              void* d_out, int out_size, void* d_ws, size_t ws_size,
                              hipStream_t stream) {
  const float* x   = (const float*)d_in[0];
  const float* qw  = (const float*)d_in[1];
  const float* kw  = (const float*)d_in[2];
  const float* vw  = (const float*)d_in[3];
  const float* qrw = (const float*)d_in[4];
  const float* krw = (const float*)d_in[5];
  const float* ow  = (const float*)d_in[6];
  float* out = (float*)d_out;

  float* ws = (float*)d_ws;
  float* Qb = ws;                                    // QSZ f32
  float* Kb = Qb + QSZ;                              // KSZ f32
  float* Vb = Kb + KSZ;                              // VSZ f32
  ushort* KhiG = (ushort*)(Vb + VSZ);                // KPK us
  ushort* KloG = KhiG + KPK;
  ushort* VhiT = KloG + KPK;
  ushort* AhiG = VhiT + KPK;                         // ASZ us
  ushort* AloG = AhiG + ASZ;
  ushort* OWhi = AloG + ASZ;                         // OWSZ us
  ushort* OWlo = OWhi + OWSZ;
  float* Mpart = (float*)(OWlo + OWSZ);              // NSLOTS*64 f32
  float* Lpart = Mpart + (size_t)NSLOTS*64;
  float* Opart = Lpart + (size_t)NSLOTS*64;          // NSLOTS*4096 f32
  // overlay (disjoint lifetimes: pack->proj vs attn->reduce):
  ushort* XhiG   = (ushort*)Opart;                   // NTOK*EMB us
  ushort* XloG   = XhiG + (size_t)NTOK*EMB;
  ushort* WcatHi = XloG + (size_t)NTOK*EMB;          // WCAT us
  ushort* WcatLo = WcatHi + WCAT;

  const size_t need = (size_t)((char*)(Opart + (size_t)NSLOTS*4096) - (char*)d_ws);
  const bool splitk = (ws_size >= need);

  // 1. pre-split x / weights / o_w to bf16 hi/lo
  {
    int total = XSEG + WSEG + OSEG;
    pack_inputs_kernel<<<(total+255)/256, 256, 0, stream>>>(
        x, qw, kw, vw, qrw, krw, ow, XhiG, XloG, WcatHi, WcatLo, OWhi, OWlo);
  }

  // 2. fused projections (MFMA split-4, pure-copy staging)
  dim3 g1((NTOK + 63)/64, 960/64);
  proj_kernel<<<g1, 256, 0, stream>>>(XhiG, XloG, WcatHi, WcatLo, Qb, Kb, Vb);

  // 3. rope on q_r / k_r
  {
    int total = NB*(NH+NKV)*S_LEN;
    rope_kernel<<<(total+255)/256, 256, 0, stream>>>(Qb, Kb);
  }

  // 4. fused quant+pack K and V
  packqk_kernel<<<NB*NKV*33, 256, 0, stream>>>(Kb, KhiG, KloG);
  packqv_kernel<<<NB*NKV*33, 256, 0, stream>>>(Vb, VhiT);

  // 5. causal flash attention (split-K) + reduce
  if (splitk) {
    dim3 ga(33, NB*NH, 5);
    attn_kernel<<<ga, 256, 0, stream>>>(Qb, KhiG, KloG, VhiT, AhiG, AloG,
                                        Opart, Mpart, Lpart, 8);
    dim3 gr(25, NB*NH);
    attn_reduce_kernel<<<gr, 256, 0, stream>>>(Opart, Mpart, Lpart, AhiG, AloG);
  } else {
    dim3 ga(33, NB*NH, 1);
    attn_kernel<<<ga, 256, 0, stream>>>(Qb, KhiG, KloG, VhiT, AhiG, AloG,
                                        Opart, Mpart, Lpart, 33);
  }

  // 6. output projection (MFMA split-3, pure-copy staging)
  dim3 go((NTOK + 63)/64, EMB/64);
  oproj_kernel<<<go, 256, 0, stream>>>(AhiG, AloG, OWhi, OWlo, out);
}